// Round 9
// baseline (813.614 us; speedup 1.0000x reference)
//
#include <hip/hip_runtime.h>
#include <hip/hip_bf16.h>
#include <cstdint>
#include <cstddef>

typedef __bf16 bf16;
typedef __bf16 bf16x8 __attribute__((ext_vector_type(8)));
typedef __bf16 bf16x4 __attribute__((ext_vector_type(4)));
typedef float  f32x4  __attribute__((ext_vector_type(4)));

typedef __attribute__((address_space(1))) void gvoid_t;
typedef __attribute__((address_space(3))) void lvoid_t;

// async global->LDS, 16B per lane; LDS dest must be wave-uniform base (HW adds lane*16)
#define GLD_LDS16(g, l) __builtin_amdgcn_global_load_lds( \
    (gvoid_t*)(uintptr_t)(g), (lvoid_t*)(uint32_t)(uintptr_t)(l), 16, 0, 0)

#define SBAR() __builtin_amdgcn_s_barrier()
#define SCHED_FENCE() __builtin_amdgcn_sched_barrier(0)
#define WAIT_VMN(n) asm volatile("s_waitcnt vmcnt(" #n ")" ::: "memory")
#define WAIT_LGKM0() asm volatile("s_waitcnt lgkmcnt(0)" ::: "memory")

// ---------------------------------------------------------------------------
// float -> OCP e4m3fn, RNE, saturating. Manual (no header dependency).
// ---------------------------------------------------------------------------
__device__ inline uint8_t to_fp8(float x)
{
  uint32_t u = __float_as_uint(x);
  const uint8_t s = (u >> 24) & 0x80u;
  const int e = (int)((u >> 23) & 0xff) - 127;
  const uint32_t m = u & 0x7fffffu;
  if (((u >> 23) & 0xff) == 0xff) return s | 0x7e;            // inf/nan -> sat
  if (e > 8 || (e == 8 && m > 0x600000u)) return s | 0x7e;    // |x|>448 -> 448
  if (e >= -6) {                                              // normal fp8
    uint32_t mant = m >> 20;
    const uint32_t rest = m & 0xfffffu;
    const uint32_t rnd = (rest > 0x80000u) || (rest == 0x80000u && (mant & 1));
    mant += rnd;
    uint32_t ee = (uint32_t)(e + 7);
    if (mant == 8) { mant = 0; ee += 1; }
    if (ee > 15 || (ee == 15 && mant > 6)) return s | 0x7e;
    return s | (ee << 3) | mant;
  }
  if (e < -10) return s;                                      // -> +-0
  const int sh = 20 + (-6 - e);                               // 21..24
  const uint32_t sig = 0x800000u | m;
  uint32_t mant = sig >> sh;
  const uint32_t rem = sig & ((1u << sh) - 1u);
  const uint32_t half = 1u << (sh - 1);
  const uint32_t rnd = (rem > half) || (rem == half && (mant & 1));
  mant += rnd;
  if (mant >= 8) return s | (1u << 3);
  return s | mant;
}

// ---------------------------------------------------------------------------
// 4x fused weight transpose + f32->bf16 cast (1024x1024 each): q,k,v -> wqkvT
// (contiguous), o -> woT.
// ---------------------------------------------------------------------------
__global__ __launch_bounds__(256) void transpose4(
    const float* __restrict__ qw, const float* __restrict__ kw,
    const float* __restrict__ vw, const float* __restrict__ ow,
    bf16* __restrict__ wqkvT, bf16* __restrict__ woT)
{
  __shared__ float tile[32][33];
  const int z = blockIdx.z;
  const float* in = z == 0 ? qw : (z == 1 ? kw : (z == 2 ? vw : ow));
  bf16* out = z == 3 ? woT : (wqkvT + (size_t)z * 1024 * 1024);
  const int bx = blockIdx.x, by = blockIdx.y;
  const int tx = threadIdx.x, ty = threadIdx.y;
#pragma unroll
  for (int i = 0; i < 32; i += 8)
    tile[ty + i][tx] = in[(size_t)(by * 32 + ty + i) * 1024 + bx * 32 + tx];
  __syncthreads();
#pragma unroll
  for (int i = 0; i < 32; i += 8)
    out[(size_t)(bx * 32 + ty + i) * 1024 + by * 32 + tx] = (bf16)tile[tx][ty + i];
}

// transpose + cast to fp8 with scale (for fc/proj weights; scale folds into epi)
__global__ __launch_bounds__(256) void transpose_cast_f8(
    const float* __restrict__ in, uint8_t* __restrict__ out, int R, int C,
    float scale)
{
  __shared__ float tile[32][33];
  const int bx = blockIdx.x, by = blockIdx.y;
  const int tx = threadIdx.x, ty = threadIdx.y;
#pragma unroll
  for (int i = 0; i < 32; i += 8)
    tile[ty + i][tx] = in[(size_t)(by * 32 + ty + i) * C + bx * 32 + tx];
  __syncthreads();
#pragma unroll
  for (int i = 0; i < 32; i += 8)
    out[(size_t)(bx * 32 + ty + i) * R + by * 32 + tx] = to_fp8(tile[tx][ty + i] * scale);
}

// pack q/k/v biases into one 3072-float vector
__global__ __launch_bounds__(256) void pack3(
    const float* __restrict__ a, const float* __restrict__ b,
    const float* __restrict__ c, float* __restrict__ o)
{
  const int i = blockIdx.x * 256 + threadIdx.x;
  o[i] = i < 1024 ? a[i] : (i < 2048 ? b[i - 1024] : c[i - 2048]);
}

// ---------------------------------------------------------------------------
// LayerNorm over H=1024, f32 in -> bf16 out (OUT8=0) or fp8 out (OUT8=1).
// ---------------------------------------------------------------------------
template <int OUT8>
__global__ __launch_bounds__(256) void ln_row(
    const float* __restrict__ x, const float* __restrict__ w,
    const float* __restrict__ b, void* __restrict__ outp)
{
  const int row = blockIdx.x;
  const int tid = threadIdx.x;
  const float4 v = ((const float4*)(x + (size_t)row * 1024))[tid];
  float s  = v.x + v.y + v.z + v.w;
  float ss = v.x * v.x + v.y * v.y + v.z * v.z + v.w * v.w;
#pragma unroll
  for (int off = 32; off > 0; off >>= 1) {
    s  += __shfl_down(s, off);
    ss += __shfl_down(ss, off);
  }
  __shared__ float red[8];
  const int wid = tid >> 6, lane = tid & 63;
  if (lane == 0) { red[wid] = s; red[4 + wid] = ss; }
  __syncthreads();
  s  = red[0] + red[1] + red[2] + red[3];
  ss = red[4] + red[5] + red[6] + red[7];
  const float mu   = s * (1.f / 1024.f);
  const float var  = ss * (1.f / 1024.f) - mu * mu;
  const float rstd = rsqrtf(var + 1e-5f);
  const float4 wv = ((const float4*)w)[tid];
  const float4 bv = ((const float4*)b)[tid];
  float o0 = (v.x - mu) * rstd * wv.x + bv.x;
  float o1 = (v.y - mu) * rstd * wv.y + bv.y;
  float o2 = (v.z - mu) * rstd * wv.z + bv.z;
  float o3 = (v.w - mu) * rstd * wv.w + bv.w;
  if constexpr (OUT8) {
    uint8_t* out = (uint8_t*)outp;
    const size_t base = (size_t)row * 1024 + tid * 4;
    uchar4 q = {to_fp8(o0), to_fp8(o1), to_fp8(o2), to_fp8(o3)};
    *(uchar4*)(out + base) = q;
  } else {
    bf16x4 ov; ov[0] = (bf16)o0; ov[1] = (bf16)o1; ov[2] = (bf16)o2; ov[3] = (bf16)o3;
    *(bf16x4*)((bf16*)outp + (size_t)row * 1024 + tid * 4) = ov;
  }
}

// ---------------------------------------------------------------------------
// 256x256 bf16 GEMM, BK=64, 8 waves (2Mx4N), r6/r7 4-phase schedule (best).
// EPI: 0 bias->bf16 | 1 bias->elu+1->bf16 | 2 bias+resid->f32 |
//      4 qkv merged (col<2048 elu+1, else plain)
// ---------------------------------------------------------------------------
template <int EPI>
__global__ __launch_bounds__(512, 2) void gemm256(
    const bf16* __restrict__ A, const bf16* __restrict__ BT,
    const float* __restrict__ bias, const float* __restrict__ resid,
    void* __restrict__ outp, int M, int N, int K, int nx)
{
  __shared__ __align__(16) char lds[131072];
  const int tid  = threadIdx.x;
  const int wid  = tid >> 6, lane = tid & 63;
  const int wr   = wid >> 2, wc = wid & 3;
  const int ln15 = lane & 15, lhi = lane >> 4;

  const int nwg = (int)gridDim.x;
  const int cpx = nwg >> 3;
  const int bid = (int)blockIdx.x;
  const int lg  = (bid & 7) * cpx + (bid >> 3);
  const int bx  = lg % nx, by = lg / nx;
  const int row0 = by << 8, col0 = bx << 8;

  const int srowA = tid >> 3;
  const int sslA  = (tid & 7) ^ (srowA & 7);
  const bf16* aS  = A + (size_t)(row0 + srowA) * K + sslA * 8;
  const size_t rjK = (size_t)K << 6;
  const int u8    = tid >> 3, s8 = tid & 7;
  const int gRowB = ((u8 >> 5) << 6) + (u8 & 31);
  const int sslB  = s8 ^ (u8 & 7);
  const bf16* bS  = BT + (size_t)(col0 + gRowB) * K + sslB * 8;

  char* ldsAw = lds + wid * 1024;
  char* ldsBw = lds + 65536 + wid * 1024;

  const int slk0 = (lhi ^ (ln15 & 7)) << 4;
  const int slk1 = ((4 + lhi) ^ (ln15 & 7)) << 4;
  const int rowA0 = ((wr << 7) + ln15) * 128;
  const int rowB0 = 65536 + (wc * 32 + ln15) * 128;

  f32x4 acc[8][4] = {};
  bf16x8 a[4][2], b0[2][2], b1[2][2];
  const int nt = K >> 6;

#define STG_A(D, KT, I) GLD_LDS16(aS + (size_t)(I) * rjK + (size_t)(KT) * 64, \
                                  ldsAw + (D) * 32768 + (I) * 8192)
#define STG_B(D, KT, NH, J) GLD_LDS16(bS + (size_t)((J) * 128 + (NH) * 32) * K + (size_t)(KT) * 64, \
                                      ldsBw + (D) * 32768 + (NH) * 16384 + (J) * 8192)
#define RD_A(D, MH) do { _Pragma("unroll") \
    for (int m_ = 0; m_ < 4; ++m_) { \
      a[m_][0] = *(const bf16x8*)(lds + (D) * 32768 + rowA0 + (MH) * 8192 + m_ * 2048 + slk0); \
      a[m_][1] = *(const bf16x8*)(lds + (D) * 32768 + rowA0 + (MH) * 8192 + m_ * 2048 + slk1); \
    } } while (0)
#define RD_B(D, NH, DST) do { _Pragma("unroll") \
    for (int n_ = 0; n_ < 2; ++n_) { \
      DST[n_][0] = *(const bf16x8*)(lds + (D) * 32768 + rowB0 + (NH) * 16384 + n_ * 2048 + slk0); \
      DST[n_][1] = *(const bf16x8*)(lds + (D) * 32768 + rowB0 + (NH) * 16384 + n_ * 2048 + slk1); \
    } } while (0)
#define MFMA8(MH, NH, BSRC) do { \
    __builtin_amdgcn_s_setprio(1); \
    _Pragma("unroll") for (int m_ = 0; m_ < 4; ++m_) \
    _Pragma("unroll") for (int n_ = 0; n_ < 2; ++n_) { \
      acc[(MH) * 4 + m_][(NH) * 2 + n_] = __builtin_amdgcn_mfma_f32_16x16x32_bf16( \
          a[m_][0], BSRC[n_][0], acc[(MH) * 4 + m_][(NH) * 2 + n_], 0, 0, 0); \
      acc[(MH) * 4 + m_][(NH) * 2 + n_] = __builtin_amdgcn_mfma_f32_16x16x32_bf16( \
          a[m_][1], BSRC[n_][1], acc[(MH) * 4 + m_][(NH) * 2 + n_], 0, 0, 0); \
    } \
    __builtin_amdgcn_s_setprio(0); } while (0)

  STG_A(0, 0, 0); STG_A(0, 0, 2);
  STG_B(0, 0, 0, 0); STG_B(0, 0, 0, 1);
  STG_B(0, 0, 1, 0); STG_B(0, 0, 1, 1);
  STG_A(0, 0, 1); STG_A(0, 0, 3);
  WAIT_VMN(0);
  SBAR(); SCHED_FENCE();

  for (int kt = 0; kt < nt - 1; ++kt) {
    const int d = kt & 1, dn = d ^ 1;
    RD_A(d, 0); RD_B(d, 0, b0);
    STG_A(dn, kt + 1, 0); STG_A(dn, kt + 1, 2);
    SBAR(); WAIT_LGKM0(); SCHED_FENCE();
    MFMA8(0, 0, b0);
    SBAR(); SCHED_FENCE();
    RD_B(d, 1, b1);
    STG_B(dn, kt + 1, 0, 0); STG_B(dn, kt + 1, 0, 1);
    WAIT_VMN(4);
    SBAR(); WAIT_LGKM0(); SCHED_FENCE();
    MFMA8(0, 1, b1);
    SBAR(); SCHED_FENCE();
    RD_A(d, 1);
    STG_B(dn, kt + 1, 1, 0); STG_B(dn, kt + 1, 1, 1);
    SBAR(); WAIT_LGKM0(); SCHED_FENCE();
    MFMA8(1, 0, b0);
    SBAR(); SCHED_FENCE();
    STG_A(dn, kt + 1, 1); STG_A(dn, kt + 1, 3);
    MFMA8(1, 1, b1);
    WAIT_VMN(2);
    SBAR(); SCHED_FENCE();
  }

  {
    const int d = (nt - 1) & 1;
    RD_A(d, 0); RD_B(d, 0, b0);
    SBAR(); WAIT_LGKM0(); SCHED_FENCE();
    MFMA8(0, 0, b0);
    SBAR(); SCHED_FENCE();
    RD_B(d, 1, b1);
    WAIT_VMN(0);
    SBAR(); WAIT_LGKM0(); SCHED_FENCE();
    MFMA8(0, 1, b1);
    SBAR(); SCHED_FENCE();
    RD_A(d, 1);
    WAIT_LGKM0(); SCHED_FENCE();
    MFMA8(1, 0, b0);
    MFMA8(1, 1, b1);
  }
#undef STG_A
#undef STG_B
#undef RD_A
#undef RD_B
#undef MFMA8

  const int lr4 = lhi << 2;
#pragma unroll
  for (int m = 0; m < 8; ++m) {
#pragma unroll
    for (int n = 0; n < 4; ++n) {
      const int c_i = col0 + wc * 64 + n * 16 + ln15;
      const float bv = bias[c_i];
#pragma unroll
      for (int j = 0; j < 4; ++j) {
        const int r_i = row0 + wr * 128 + m * 16 + lr4 + j;
        const size_t idx = (size_t)r_i * N + c_i;
        float val = acc[m][n][j] + bv;
        if constexpr (EPI == 0) {
          ((bf16*)outp)[idx] = (bf16)val;
        } else if constexpr (EPI == 1) {
          ((bf16*)outp)[idx] = (bf16)(val > 0.f ? val + 1.f : __expf(val));
        } else if constexpr (EPI == 2) {
          ((float*)outp)[idx] = val + resid[idx];
        } else {
          if (c_i < 2048)
            ((bf16*)outp)[idx] = (bf16)(val > 0.f ? val + 1.f : __expf(val));
          else
            ((bf16*)outp)[idx] = (bf16)val;
        }
      }
    }
  }
}

// ---------------------------------------------------------------------------
// 256x256 fp8-e4m3 GEMM, BK=64, 8 waves (2Mx4N), 16x16x32 fp8_fp8 MFMA.
// Weights pre-scaled x4 -> epilogue multiplies acc by 0.25.
// LDS 64KB: dbuf x {A,B} [256 rows][64B] fp8; 4x16B slots/row, XOR swizzle
// slot^=(row&3) on BOTH gld source and ds_read (b64 frag reads, conflict-free).
// Single-phase/tile (r3 style): stage next tile at top, 24 b64 reads, 64 MFMA,
// vm0 (stages issued a full tile earlier) + barrier.
// EPI: 2 = 0.25*acc + bias + resid -> f32 | 3 = 0.25*acc + bias -> gelu -> fp8
// ---------------------------------------------------------------------------
template <int EPI>
__global__ __launch_bounds__(512, 2) void gemm256f8(
    const uint8_t* __restrict__ A, const uint8_t* __restrict__ BT,
    const float* __restrict__ bias, const float* __restrict__ resid,
    void* __restrict__ outp, int M, int N, int K, int nx)
{
  __shared__ __align__(16) char lds[65536];
  const int tid  = threadIdx.x;
  const int wid  = tid >> 6, lane = tid & 63;
  const int wr   = wid >> 2, wc = wid & 3;
  const int ln15 = lane & 15, lhi = lane >> 4;

  const int nwg = (int)gridDim.x;
  const int cpx = nwg >> 3;
  const int bid = (int)blockIdx.x;
  const int lg  = (bid & 7) * cpx + (bid >> 3);
  const int bx  = lg % nx, by = lg / nx;
  const int row0 = by << 8, col0 = bx << 8;

  // staging: thread covers row srow=tid>>2 (64B), LDS slot tid&3 holds
  // global slot (tid&3)^(srow&3). Two issues per matrix: rows +0 / +128.
  const int srow  = tid >> 2;                  // 0..127
  const int sslot = (tid & 3) ^ (srow & 3);
  const uint8_t* aS = A  + (size_t)(row0 + srow) * K + sslot * 16;
  const uint8_t* bS = BT + (size_t)(col0 + srow) * K + sslot * 16;
  const size_t rjump = (size_t)K << 7;         // +128 rows (bytes)
  char* ldsW = lds + wid * 1024;

  // read offsets: global 16B-slot g = ks*2 + (lhi>>1); sub-byte (lhi&1)*8
  const int sub  = (lhi & 1) * 8;
  const int g0   = lhi >> 1;
  const int slkK0 = ((g0) ^ (ln15 & 3)) * 16 + sub;
  const int slkK1 = ((2 + g0) ^ (ln15 & 3)) * 16 + sub;
  const int rowA0 = (wr * 128 + ln15) * 64;
  const int rowB0 = 32768 + (wc * 64 + ln15) * 64;

  f32x4 acc[8][4] = {};
  const int nt = K >> 6;

#define STG8(D, KT) do { \
    const uint8_t* ga_ = aS + (size_t)(KT) * 64; \
    const uint8_t* gb_ = bS + (size_t)(KT) * 64; \
    char* la_ = ldsW + (D) * 16384; \
    GLD_LDS16(ga_,         la_); \
    GLD_LDS16(ga_ + rjump, la_ + 8192); \
    GLD_LDS16(gb_,         la_ + 32768); \
    GLD_LDS16(gb_ + rjump, la_ + 40960); \
  } while (0)

  STG8(0, 0);
  WAIT_VMN(0);
  SBAR();

  for (int kt = 0; kt < nt; ++kt) {
    const int d = kt & 1;
    const char* base = (const char*)lds + d * 16384;
    if (kt + 1 < nt) STG8(d ^ 1, kt + 1);

    long a0v[8], b0v[4], a1v[8], b1v[4];
#pragma unroll
    for (int m = 0; m < 8; ++m) a0v[m] = *(const long*)(base + rowA0 + m * 1024 + slkK0);
#pragma unroll
    for (int n = 0; n < 4; ++n) b0v[n] = *(const long*)(base + rowB0 + n * 1024 + slkK0);
#pragma unroll
    for (int m = 0; m < 8; ++m) a1v[m] = *(const long*)(base + rowA0 + m * 1024 + slkK1);
#pragma unroll
    for (int n = 0; n < 4; ++n) b1v[n] = *(const long*)(base + rowB0 + n * 1024 + slkK1);

    __builtin_amdgcn_s_setprio(1);
#pragma unroll
    for (int m = 0; m < 8; ++m)
#pragma unroll
      for (int n = 0; n < 4; ++n)
        acc[m][n] = __builtin_amdgcn_mfma_f32_16x16x32_fp8_fp8(a0v[m], b0v[n], acc[m][n], 0, 0, 0);
#pragma unroll
    for (int m = 0; m < 8; ++m)
#pragma unroll
      for (int n = 0; n < 4; ++n)
        acc[m][n] = __builtin_amdgcn_mfma_f32_16x16x32_fp8_fp8(a1v[m], b1v[n], acc[m][n], 0, 0, 0);
    __builtin_amdgcn_s_setprio(0);

    WAIT_VMN(0);   // stages issued a full tile ago
    SBAR();
  }
#undef STG8

  const int lr4 = lhi << 2;
#pragma unroll
  for (int m = 0; m < 8; ++m) {
#pragma unroll
    for (int n = 0; n < 4; ++n) {
      const int c_i = col0 + wc * 64 + n * 16 + ln15;
      const float bv = bias[c_i];
#pragma unroll
      for (int j = 0; j < 4; ++j) {
        const int r_i = row0 + wr * 128 + m * 16 + lr4 + j;
        const size_t idx = (size_t)r_i * N + c_i;
        float val = acc[m][n][j] * 0.25f + bv;   // undo x4 weight scale
        if constexpr (EPI == 2) {
          ((float*)outp)[idx] = val + resid[idx];
        } else {
          const float u  = 0.7978845608028654f * (val + 0.044715f * val * val * val);
          const float th = 1.f - 2.f / (__expf(2.f * u) + 1.f);
          ((uint8_t*)outp)[idx] = to_fp8(0.5f * val * (1.f + th));
        }
      }
    }
  }
}

// ---------------------------------------------------------------------------
// kv partials, roles swapped so output is kvT[e][d] = sum_t v[t,e]*kf[t,d].
// ---------------------------------------------------------------------------
__global__ __launch_bounds__(256) void kv_part_kernel(
    const bf16* __restrict__ qkv, float* __restrict__ kv_part,
    float* __restrict__ ksum_part)
{
  const int bh = blockIdx.x >> 3, ch = blockIdx.x & 7;
  const int b = bh >> 4, h = bh & 15;
  const int tid = threadIdx.x;
  const int d = tid & 63, eg = tid >> 6;
  const size_t grow0 = (size_t)b * 4096 + (size_t)ch * 512;
  const size_t vbase = 2048 + (size_t)h * 64;
  __shared__ bf16 svv[8][64], skf[8][64];
  float accum[16];
#pragma unroll
  for (int i = 0; i < 16; ++i) accum[i] = 0.f;
  float ks = 0.f;
  const int tt = tid >> 5, cc = (tid & 31) << 1;
  for (int t0 = 0; t0 < 512; t0 += 8) {
    __syncthreads();
    const size_t base = (grow0 + t0 + tt) * 3072 + vbase + cc;
    *(uint32_t*)&svv[tt][cc] = *(const uint32_t*)(qkv + base);          // V
    *(uint32_t*)&skf[tt][cc] = *(const uint32_t*)(qkv + base - 1024);   // KF
    __syncthreads();
#pragma unroll
    for (int q = 0; q < 8; ++q) {
      const float kd = (float)skf[q][d];
      const uint32_t* u0 = (const uint32_t*)&svv[q][eg * 16];
#pragma unroll
      for (int i = 0; i < 8; ++i) {
        const uint32_t u = u0[i];
        const float lo = __uint_as_float(u << 16);
        const float hi = __uint_as_float(u & 0xffff0000u);
        accum[2 * i]     += lo * kd;
        accum[2 * i + 1] += hi * kd;
      }
    }
    if (tid < 64) {
#pragma unroll
      for (int q = 0; q < 8; ++q) ks += (float)skf[q][tid];
    }
  }
  float* op = kv_part + (size_t)blockIdx.x * 4096 + (size_t)(eg * 16) * 64 + d;
#pragma unroll
  for (int ee = 0; ee < 16; ++ee) op[ee * 64] = accum[ee];
  if (tid < 64) ksum_part[(size_t)blockIdx.x * 64 + tid] = ks;
}

// ---------------------------------------------------------------------------
// reduce partials -> bf16 B-tile KB[80][64] per head:
// rows 0-63 = kvT[e][d], row 64 = ksum[d], rows 65-79 = 0.
// ---------------------------------------------------------------------------
__global__ __launch_bounds__(256) void kv_reduce(
    const float* __restrict__ kvp, const float* __restrict__ ksp,
    bf16* __restrict__ kb)
{
  const int bh = blockIdx.x;
  const int tid = threadIdx.x;
  bf16* KB = kb + (size_t)bh * 5120;
  for (int i = tid; i < 4096; i += 256) {
    float s = 0.f;
#pragma unroll
    for (int ch = 0; ch < 8; ++ch) s += kvp[((size_t)bh * 8 + ch) * 4096 + i];
    KB[i] = (bf16)s;
  }
  if (tid < 64) {
    float s = 0.f;
#pragma unroll
    for (int ch = 0; ch < 8; ++ch) s += ksp[((size_t)bh * 8 + ch) * 64 + tid];
    KB[4096 + tid] = (bf16)s;
  }
  for (int i = 4160 + tid; i < 5120; i += 256) KB[i] = (bf16)0.f;
}

// ---------------------------------------------------------------------------
// attn out via MFMA (16x16x32): out[r][e] = (qf.kvT)[r][e] / (qf.ksum + 1e-6)
// ---------------------------------------------------------------------------
__global__ __launch_bounds__(256) void attn_mfma(
    const bf16* __restrict__ qkv, const bf16* __restrict__ kb,
    bf16* __restrict__ attn)
{
  const int bh = blockIdx.x >> 4, rb = blockIdx.x & 15;
  const int b = bh >> 4, h = bh & 15;
  const int tid = threadIdx.x, wid = tid >> 6, lane = tid & 63;
  const int ln15 = lane & 15, lhi = lane >> 4;
  const size_t row0 = (size_t)b * 4096 + rb * 256 + wid * 64;
  const bf16* KB = kb + (size_t)bh * 5120;

  bf16x8 bfr[5][2];
#pragma unroll
  for (int nb = 0; nb < 5; ++nb)
#pragma unroll
    for (int ks = 0; ks < 2; ++ks)
      bfr[nb][ks] = *(const bf16x8*)(KB + (nb * 16 + ln15) * 64 + ks * 32 + lhi * 8);

  for (int mt = 0; mt < 4; ++mt) {
    const bf16* ap = qkv + (row0 + mt * 16 + ln15) * 3072 + h * 64 + lhi * 8;
    const bf16x8 a0 = *(const bf16x8*)ap;
    const bf16x8 a1 = *(const bf16x8*)(ap + 32);
    f32x4 acc[5];
#pragma unroll
    for (int nb = 0; nb < 5; ++nb) {
      f32x4 z = {0.f, 0.f, 0.f, 0.f};
      z = __builtin_amdgcn_mfma_f32_16x16x32_bf16(a0, bfr[nb][0], z, 0, 0, 0);
      acc[nb] = __builtin_amdgcn_mfma_f32_16x16x32_bf16(a1, bfr[nb][1], z, 0, 0, 0);
    }
#pragma unroll
    for (int j = 0; j < 4; ++j) {
      const float ns = __shfl(acc[4][j], (lane & 48));
      const float inv = 1.f / (ns + 1e-6f);
      const size_t r = row0 + mt * 16 + (lhi << 2) + j;
#pragma unroll
      for (int nb = 0; nb < 4; ++nb)
        attn[r * 1024 + h * 64 + nb * 16 + ln15] = (bf16)(acc[nb][j] * inv);
    }
  }
}

// ---------------------------------------------------------------------------
// launch
// ---------------------------------------------------------------------------
extern "C" void kernel_launch(void* const* d_in, const int* in_sizes, int n_in,
                              void* d_out, int out_size, void* d_ws, size_t ws_size,
                              hipStream_t stream)
{
  const float* x    = (const float*)d_in[0];
  const float* ln1w = (const float*)d_in[1];
  const float* ln1b = (const float*)d_in[2];
  const float* qw   = (const float*)d_in[3];
  const float* qb   = (const float*)d_in[4];
  const float* kw   = (const float*)d_in[5];
  const float* kb_  = (const float*)d_in[6];
  const float* vw   = (const float*)d_in[7];
  const float* vb   = (const float*)d_in[8];
  const float* ow   = (const float*)d_in[9];
  const float* ob   = (const float*)d_in[10];
  const float* ln2w = (const float*)d_in[11];
  const float* ln2b = (const float*)d_in[12];
  const float* fcw  = (const float*)d_in[13];
  const float* fcb  = (const float*)d_in[14];
  const float* pjw  = (const float*)d_in[15];
  const float* pjb  = (const float*)d_in[16];
  float* out = (float*)d_out;
  char* ws = (char*)d_ws;

  constexpr size_t O_LNX  = 0;
  constexpr size_t O_QKV  = 33554432;
  constexpr size_t O_HMLP = 0;           // fp8 hmlp, 64MB
  constexpr size_t O_KVP  = 134217728;
  constexpr size_t O_KSP  = 142606336;
  constexpr size_t O_KB   = 142737408;
  constexpr size_t O_ATTN = 143802368;
  constexpr size_t O_LN2  = 177356800;   // fp8 ln2h, 16MB
  constexpr size_t O_WQ   = 210911232;
  constexpr size_t O_WO   = 217202688;
  constexpr size_t O_WFC  = 219299840;   // fp8 fc weight, 4MB
  constexpr size_t O_WPJ  = 227688448;   // fp8 proj weight, 4MB

  bf16* lnx    = (bf16*)(ws + O_LNX);
  bf16* qkv    = (bf16*)(ws + O_QKV);
  uint8_t* hmlp8 = (uint8_t*)(ws + O_HMLP);
  float* kvp   = (float*)(ws + O_KVP);
  float* qkvb  = (float*)(ws + O_KVP);   // 12KB, dead before kv_part runs
  float* ksp   = (float*)(ws + O_KSP);
  bf16* kbt    = (bf16*)(ws + O_KB);
  bf16* attn   = (bf16*)(ws + O_ATTN);
  uint8_t* ln2h8 = (uint8_t*)(ws + O_LN2);
  bf16* wqkvT  = (bf16*)(ws + O_WQ);
  bf16* woT    = (bf16*)(ws + O_WO);
  uint8_t* wfc8 = (uint8_t*)(ws + O_WFC);
  uint8_t* wpj8 = (uint8_t*)(ws + O_WPJ);

  const dim3 tb(32, 8);
  transpose4<<<dim3(32, 32, 4), tb, 0, stream>>>(qw, kw, vw, ow, wqkvT, woT);
  transpose_cast_f8<<<dim3(128, 32), tb, 0, stream>>>(fcw, wfc8, 1024, 4096, 4.f);
  transpose_cast_f8<<<dim3(32, 128), tb, 0, stream>>>(pjw, wpj8, 4096, 1024, 4.f);
  pack3<<<12, 256, 0, stream>>>(qb, kb_, vb, qkvb);

  ln_row<0><<<16384, 256, 0, stream>>>(x, ln1w, ln1b, lnx);

  // fused q|k|v projection: [16384,1024] x [1024,3072] (bf16)
  gemm256<4><<<768, 512, 0, stream>>>(lnx, wqkvT, qkvb, nullptr, qkv, 16384, 3072, 1024, 12);

  kv_part_kernel<<<512, 256, 0, stream>>>(qkv, kvp, ksp);
  kv_reduce<<<64, 256, 0, stream>>>(kvp, ksp, kbt);
  attn_mfma<<<1024, 256, 0, stream>>>(qkv, kbt, attn);

  // y1 = x + attn @ o_w + o_b   (f32 into d_out, bf16 GEMM)
  gemm256<2><<<256, 512, 0, stream>>>(attn, woT, ob, x, out, 16384, 1024, 1024, 4);

  ln_row<1><<<16384, 256, 0, stream>>>(out, ln2w, ln2b, ln2h8);

  // fc: fp8 x fp8 -> gelu -> fp8 hmlp
  gemm256f8<3><<<1024, 512, 0, stream>>>(ln2h8, wfc8, fcb, nullptr, hmlp8, 16384, 4096, 1024, 16);

  // proj: fp8 x fp8 + resid -> f32 (in-place on d_out: read-before-write)
  gemm256f8<2><<<256, 512, 0, stream>>>(hmlp8, wpj8, pjb, out, out, 16384, 1024, 4096, 4);
}

// Round 10
// 765.678 us; speedup vs baseline: 1.0626x; 1.0626x over previous
//
#include <hip/hip_runtime.h>
#include <hip/hip_bf16.h>
#include <cstdint>
#include <cstddef>

typedef __bf16 bf16;
typedef __bf16 bf16x8 __attribute__((ext_vector_type(8)));
typedef __bf16 bf16x4 __attribute__((ext_vector_type(4)));
typedef float  f32x4  __attribute__((ext_vector_type(4)));

typedef __attribute__((address_space(1))) void gvoid_t;
typedef __attribute__((address_space(3))) void lvoid_t;

// async global->LDS, 16B per lane; LDS dest must be wave-uniform base (HW adds lane*16)
#define GLD_LDS16(g, l) __builtin_amdgcn_global_load_lds( \
    (gvoid_t*)(uintptr_t)(g), (lvoid_t*)(uint32_t)(uintptr_t)(l), 16, 0, 0)

#define SBAR() __builtin_amdgcn_s_barrier()
#define SCHED_FENCE() __builtin_amdgcn_sched_barrier(0)
#define WAIT_VMN(n) asm volatile("s_waitcnt vmcnt(" #n ")" ::: "memory")
#define WAIT_LGKM0() asm volatile("s_waitcnt lgkmcnt(0)" ::: "memory")

// ---------------------------------------------------------------------------
// float -> OCP e4m3fn, RNE, saturating.
// ---------------------------------------------------------------------------
__device__ inline uint8_t to_fp8(float x)
{
  uint32_t u = __float_as_uint(x);
  const uint8_t s = (u >> 24) & 0x80u;
  const int e = (int)((u >> 23) & 0xff) - 127;
  const uint32_t m = u & 0x7fffffu;
  if (((u >> 23) & 0xff) == 0xff) return s | 0x7e;            // inf/nan -> sat
  if (e > 8 || (e == 8 && m > 0x600000u)) return s | 0x7e;    // |x|>448 -> 448
  if (e >= -6) {                                              // normal fp8
    uint32_t mant = m >> 20;
    const uint32_t rest = m & 0xfffffu;
    const uint32_t rnd = (rest > 0x80000u) || (rest == 0x80000u && (mant & 1));
    mant += rnd;
    uint32_t ee = (uint32_t)(e + 7);
    if (mant == 8) { mant = 0; ee += 1; }
    if (ee > 15 || (ee == 15 && mant > 6)) return s | 0x7e;
    return s | (ee << 3) | mant;
  }
  if (e < -10) return s;                                      // -> +-0
  const int sh = 20 + (-6 - e);                               // 21..24
  const uint32_t sig = 0x800000u | m;
  uint32_t mant = sig >> sh;
  const uint32_t rem = sig & ((1u << sh) - 1u);
  const uint32_t half = 1u << (sh - 1);
  const uint32_t rnd = (rem > half) || (rem == half && (mant & 1));
  mant += rnd;
  if (mant >= 8) return s | (1u << 3);
  return s | mant;
}

// ---------------------------------------------------------------------------
// 4x fused weight transpose + f32->bf16 cast (1024x1024 each)
// ---------------------------------------------------------------------------
__global__ __launch_bounds__(256) void transpose4(
    const float* __restrict__ qw, const float* __restrict__ kw,
    const float* __restrict__ vw, const float* __restrict__ ow,
    bf16* __restrict__ wqkvT, bf16* __restrict__ woT)
{
  __shared__ float tile[32][33];
  const int z = blockIdx.z;
  const float* in = z == 0 ? qw : (z == 1 ? kw : (z == 2 ? vw : ow));
  bf16* out = z == 3 ? woT : (wqkvT + (size_t)z * 1024 * 1024);
  const int bx = blockIdx.x, by = blockIdx.y;
  const int tx = threadIdx.x, ty = threadIdx.y;
#pragma unroll
  for (int i = 0; i < 32; i += 8)
    tile[ty + i][tx] = in[(size_t)(by * 32 + ty + i) * 1024 + bx * 32 + tx];
  __syncthreads();
#pragma unroll
  for (int i = 0; i < 32; i += 8)
    out[(size_t)(bx * 32 + ty + i) * 1024 + by * 32 + tx] = (bf16)tile[tx][ty + i];
}

// transpose + cast to fp8 with scale (for fc/proj weights; scale folds into epi)
__global__ __launch_bounds__(256) void transpose_cast_f8(
    const float* __restrict__ in, uint8_t* __restrict__ out, int R, int C,
    float scale)
{
  __shared__ float tile[32][33];
  const int bx = blockIdx.x, by = blockIdx.y;
  const int tx = threadIdx.x, ty = threadIdx.y;
#pragma unroll
  for (int i = 0; i < 32; i += 8)
    tile[ty + i][tx] = in[(size_t)(by * 32 + ty + i) * C + bx * 32 + tx];
  __syncthreads();
#pragma unroll
  for (int i = 0; i < 32; i += 8)
    out[(size_t)(bx * 32 + ty + i) * R + by * 32 + tx] = to_fp8(tile[tx][ty + i] * scale);
}

// pack q/k/v biases into one 3072-float vector
__global__ __launch_bounds__(256) void pack3(
    const float* __restrict__ a, const float* __restrict__ b,
    const float* __restrict__ c, float* __restrict__ o)
{
  const int i = blockIdx.x * 256 + threadIdx.x;
  o[i] = i < 1024 ? a[i] : (i < 2048 ? b[i - 1024] : c[i - 2048]);
}

// ---------------------------------------------------------------------------
// LayerNorm over H=1024, f32 in -> bf16 out (OUT8=0) or fp8 out (OUT8=1).
// ---------------------------------------------------------------------------
template <int OUT8>
__global__ __launch_bounds__(256) void ln_row(
    const float* __restrict__ x, const float* __restrict__ w,
    const float* __restrict__ b, void* __restrict__ outp)
{
  const int row = blockIdx.x;
  const int tid = threadIdx.x;
  const float4 v = ((const float4*)(x + (size_t)row * 1024))[tid];
  float s  = v.x + v.y + v.z + v.w;
  float ss = v.x * v.x + v.y * v.y + v.z * v.z + v.w * v.w;
#pragma unroll
  for (int off = 32; off > 0; off >>= 1) {
    s  += __shfl_down(s, off);
    ss += __shfl_down(ss, off);
  }
  __shared__ float red[8];
  const int wid = tid >> 6, lane = tid & 63;
  if (lane == 0) { red[wid] = s; red[4 + wid] = ss; }
  __syncthreads();
  s  = red[0] + red[1] + red[2] + red[3];
  ss = red[4] + red[5] + red[6] + red[7];
  const float mu   = s * (1.f / 1024.f);
  const float var  = ss * (1.f / 1024.f) - mu * mu;
  const float rstd = rsqrtf(var + 1e-5f);
  const float4 wv = ((const float4*)w)[tid];
  const float4 bv = ((const float4*)b)[tid];
  float o0 = (v.x - mu) * rstd * wv.x + bv.x;
  float o1 = (v.y - mu) * rstd * wv.y + bv.y;
  float o2 = (v.z - mu) * rstd * wv.z + bv.z;
  float o3 = (v.w - mu) * rstd * wv.w + bv.w;
  if constexpr (OUT8) {
    uint8_t* out = (uint8_t*)outp;
    const size_t base = (size_t)row * 1024 + tid * 4;
    uchar4 q = {to_fp8(o0), to_fp8(o1), to_fp8(o2), to_fp8(o3)};
    *(uchar4*)(out + base) = q;
  } else {
    bf16x4 ov; ov[0] = (bf16)o0; ov[1] = (bf16)o1; ov[2] = (bf16)o2; ov[3] = (bf16)o3;
    *(bf16x4*)((bf16*)outp + (size_t)row * 1024 + tid * 4) = ov;
  }
}

// ---------------------------------------------------------------------------
// 256x256 bf16 GEMM, BK=64, 8 waves (2Mx4N), r6/r7 4-phase schedule (best).
// EPI: 0 bias->bf16 | 1 bias->elu+1->bf16 | 2 bias+resid->f32 |
//      4 qkv merged (col<2048 elu+1, else plain)
// ---------------------------------------------------------------------------
template <int EPI>
__global__ __launch_bounds__(512, 2) void gemm256(
    const bf16* __restrict__ A, const bf16* __restrict__ BT,
    const float* __restrict__ bias, const float* __restrict__ resid,
    void* __restrict__ outp, int M, int N, int K, int nx)
{
  __shared__ __align__(16) char lds[131072];
  const int tid  = threadIdx.x;
  const int wid  = tid >> 6, lane = tid & 63;
  const int wr   = wid >> 2, wc = wid & 3;
  const int ln15 = lane & 15, lhi = lane >> 4;

  const int nwg = (int)gridDim.x;
  const int cpx = nwg >> 3;
  const int bid = (int)blockIdx.x;
  const int lg  = (bid & 7) * cpx + (bid >> 3);
  const int bx  = lg % nx, by = lg / nx;
  const int row0 = by << 8, col0 = bx << 8;

  const int srowA = tid >> 3;
  const int sslA  = (tid & 7) ^ (srowA & 7);
  const bf16* aS  = A + (size_t)(row0 + srowA) * K + sslA * 8;
  const size_t rjK = (size_t)K << 6;
  const int u8    = tid >> 3, s8 = tid & 7;
  const int gRowB = ((u8 >> 5) << 6) + (u8 & 31);
  const int sslB  = s8 ^ (u8 & 7);
  const bf16* bS  = BT + (size_t)(col0 + gRowB) * K + sslB * 8;

  char* ldsAw = lds + wid * 1024;
  char* ldsBw = lds + 65536 + wid * 1024;

  const int slk0 = (lhi ^ (ln15 & 7)) << 4;
  const int slk1 = ((4 + lhi) ^ (ln15 & 7)) << 4;
  const int rowA0 = ((wr << 7) + ln15) * 128;
  const int rowB0 = 65536 + (wc * 32 + ln15) * 128;

  f32x4 acc[8][4] = {};
  bf16x8 a[4][2], b0[2][2], b1[2][2];
  const int nt = K >> 6;

#define STG_A(D, KT, I) GLD_LDS16(aS + (size_t)(I) * rjK + (size_t)(KT) * 64, \
                                  ldsAw + (D) * 32768 + (I) * 8192)
#define STG_B(D, KT, NH, J) GLD_LDS16(bS + (size_t)((J) * 128 + (NH) * 32) * K + (size_t)(KT) * 64, \
                                      ldsBw + (D) * 32768 + (NH) * 16384 + (J) * 8192)
#define RD_A(D, MH) do { _Pragma("unroll") \
    for (int m_ = 0; m_ < 4; ++m_) { \
      a[m_][0] = *(const bf16x8*)(lds + (D) * 32768 + rowA0 + (MH) * 8192 + m_ * 2048 + slk0); \
      a[m_][1] = *(const bf16x8*)(lds + (D) * 32768 + rowA0 + (MH) * 8192 + m_ * 2048 + slk1); \
    } } while (0)
#define RD_B(D, NH, DST) do { _Pragma("unroll") \
    for (int n_ = 0; n_ < 2; ++n_) { \
      DST[n_][0] = *(const bf16x8*)(lds + (D) * 32768 + rowB0 + (NH) * 16384 + n_ * 2048 + slk0); \
      DST[n_][1] = *(const bf16x8*)(lds + (D) * 32768 + rowB0 + (NH) * 16384 + n_ * 2048 + slk1); \
    } } while (0)
#define MFMA8(MH, NH, BSRC) do { \
    __builtin_amdgcn_s_setprio(1); \
    _Pragma("unroll") for (int m_ = 0; m_ < 4; ++m_) \
    _Pragma("unroll") for (int n_ = 0; n_ < 2; ++n_) { \
      acc[(MH) * 4 + m_][(NH) * 2 + n_] = __builtin_amdgcn_mfma_f32_16x16x32_bf16( \
          a[m_][0], BSRC[n_][0], acc[(MH) * 4 + m_][(NH) * 2 + n_], 0, 0, 0); \
      acc[(MH) * 4 + m_][(NH) * 2 + n_] = __builtin_amdgcn_mfma_f32_16x16x32_bf16( \
          a[m_][1], BSRC[n_][1], acc[(MH) * 4 + m_][(NH) * 2 + n_], 0, 0, 0); \
    } \
    __builtin_amdgcn_s_setprio(0); } while (0)

  STG_A(0, 0, 0); STG_A(0, 0, 2);
  STG_B(0, 0, 0, 0); STG_B(0, 0, 0, 1);
  STG_B(0, 0, 1, 0); STG_B(0, 0, 1, 1);
  STG_A(0, 0, 1); STG_A(0, 0, 3);
  WAIT_VMN(0);
  SBAR(); SCHED_FENCE();

  for (int kt = 0; kt < nt - 1; ++kt) {
    const int d = kt & 1, dn = d ^ 1;
    RD_A(d, 0); RD_B(d, 0, b0);
    STG_A(dn, kt + 1, 0); STG_A(dn, kt + 1, 2);
    SBAR(); WAIT_LGKM0(); SCHED_FENCE();
    MFMA8(0, 0, b0);
    SBAR(); SCHED_FENCE();
    RD_B(d, 1, b1);
    STG_B(dn, kt + 1, 0, 0); STG_B(dn, kt + 1, 0, 1);
    WAIT_VMN(4);
    SBAR(); WAIT_LGKM0(); SCHED_FENCE();
    MFMA8(0, 1, b1);
    SBAR(); SCHED_FENCE();
    RD_A(d, 1);
    STG_B(dn, kt + 1, 1, 0); STG_B(dn, kt + 1, 1, 1);
    SBAR(); WAIT_LGKM0(); SCHED_FENCE();
    MFMA8(1, 0, b0);
    SBAR(); SCHED_FENCE();
    STG_A(dn, kt + 1, 1); STG_A(dn, kt + 1, 3);
    MFMA8(1, 1, b1);
    WAIT_VMN(2);
    SBAR(); SCHED_FENCE();
  }

  {
    const int d = (nt - 1) & 1;
    RD_A(d, 0); RD_B(d, 0, b0);
    SBAR(); WAIT_LGKM0(); SCHED_FENCE();
    MFMA8(0, 0, b0);
    SBAR(); SCHED_FENCE();
    RD_B(d, 1, b1);
    WAIT_VMN(0);
    SBAR(); WAIT_LGKM0(); SCHED_FENCE();
    MFMA8(0, 1, b1);
    SBAR(); SCHED_FENCE();
    RD_A(d, 1);
    WAIT_LGKM0(); SCHED_FENCE();
    MFMA8(1, 0, b0);
    MFMA8(1, 1, b1);
  }
#undef STG_A
#undef STG_B
#undef RD_A
#undef RD_B
#undef MFMA8

  const int lr4 = lhi << 2;
#pragma unroll
  for (int m = 0; m < 8; ++m) {
#pragma unroll
    for (int n = 0; n < 4; ++n) {
      const int c_i = col0 + wc * 64 + n * 16 + ln15;
      const float bv = bias[c_i];
#pragma unroll
      for (int j = 0; j < 4; ++j) {
        const int r_i = row0 + wr * 128 + m * 16 + lr4 + j;
        const size_t idx = (size_t)r_i * N + c_i;
        float val = acc[m][n][j] + bv;
        if constexpr (EPI == 0) {
          ((bf16*)outp)[idx] = (bf16)val;
        } else if constexpr (EPI == 1) {
          ((bf16*)outp)[idx] = (bf16)(val > 0.f ? val + 1.f : __expf(val));
        } else if constexpr (EPI == 2) {
          ((float*)outp)[idx] = val + resid[idx];
        } else {
          if (c_i < 2048)
            ((bf16*)outp)[idx] = (bf16)(val > 0.f ? val + 1.f : __expf(val));
          else
            ((bf16*)outp)[idx] = (bf16)val;
        }
      }
    }
  }
}

// ---------------------------------------------------------------------------
// 256x256 fp8-e4m3 GEMM v2: BK=128 (128B rows) -> byte-identical LDS geometry
// to the proven bf16 kernel (8x16B slots/row, slot^=(row&7), same stage units,
// same 4-phase ledger). Frag reads are b64: byte = row*128 +
// ((ks*2+(lhi>>1))^(row&7))*16 + (lhi&1)*8  (2-way bank alias max = free).
// 4 k-steps x 32 MFMA 16x16x32_fp8_fp8 per phase. Weights pre-scaled x4 ->
// epilogue x0.25. EPI: 2 = +bias+resid->f32 | 3 = +bias->gelu->fp8
// ---------------------------------------------------------------------------
template <int EPI>
__global__ __launch_bounds__(512, 2) void gemm256f8(
    const uint8_t* __restrict__ A, const uint8_t* __restrict__ BT,
    const float* __restrict__ bias, const float* __restrict__ resid,
    void* __restrict__ outp, int M, int N, int K, int nx)
{
  __shared__ __align__(16) char lds[131072];
  const int tid  = threadIdx.x;
  const int wid  = tid >> 6, lane = tid & 63;
  const int wr   = wid >> 2, wc = wid & 3;
  const int ln15 = lane & 15, lhi = lane >> 4;

  const int nwg = (int)gridDim.x;
  const int cpx = nwg >> 3;
  const int bid = (int)blockIdx.x;
  const int lg  = (bid & 7) * cpx + (bid >> 3);
  const int bx  = lg % nx, by = lg / nx;
  const int row0 = by << 8, col0 = bx << 8;

  // staging (byte-identical to bf16): thread covers row tid>>3 of a 64-row
  // chunk, 16B slot (tid&7) holding global slot (tid&7)^(row&7).
  const int srowA = tid >> 3;
  const int sslA  = (tid & 7) ^ (srowA & 7);
  const uint8_t* aS = A + (size_t)(row0 + srowA) * K + sslA * 16;
  const size_t rjK = (size_t)K << 6;          // 64 rows (bytes)
  const int u8    = tid >> 3, s8 = tid & 7;
  const int gRowB = ((u8 >> 5) << 6) + (u8 & 31);
  const int sslB  = s8 ^ (u8 & 7);
  const uint8_t* bS = BT + (size_t)(col0 + gRowB) * K + sslB * 16;

  char* ldsAw = lds + wid * 1024;
  char* ldsBw = lds + 65536 + wid * 1024;

  // read offsets: per k-step swizzled slot+sub byte
  const int e7 = ln15 & 7;
  const int sub = (lhi & 1) * 8;
  const int g0  = lhi >> 1;
  const int slkf0 = ((0 + g0) ^ e7) * 16 + sub;
  const int slkf1 = ((2 + g0) ^ e7) * 16 + sub;
  const int slkf2 = ((4 + g0) ^ e7) * 16 + sub;
  const int slkf3 = ((6 + g0) ^ e7) * 16 + sub;
  const int rowA0 = wr * 16384 + ln15 * 128;            // + MH*8192 + m*2048
  const int rowB0 = 65536 + wc * 4096 + ln15 * 128;     // + NH*16384 + n*2048

  f32x4 acc[8][4] = {};
  long a[4][4], b0[2][4], b1[2][4];
  const int nt = K >> 7;

#define STG_A8(D, KT, I) GLD_LDS16(aS + (size_t)(I) * rjK + (size_t)(KT) * 128, \
                                   ldsAw + (D) * 32768 + (I) * 8192)
#define STG_B8(D, KT, NH, J) GLD_LDS16(bS + (size_t)((J) * 128 + (NH) * 32) * K + (size_t)(KT) * 128, \
                                       ldsBw + (D) * 32768 + (NH) * 16384 + (J) * 8192)
#define RD_A8(D, MH) do { _Pragma("unroll") \
    for (int m_ = 0; m_ < 4; ++m_) { \
      const char* p_ = lds + (D) * 32768 + rowA0 + (MH) * 8192 + m_ * 2048; \
      a[m_][0] = *(const long*)(p_ + slkf0); \
      a[m_][1] = *(const long*)(p_ + slkf1); \
      a[m_][2] = *(const long*)(p_ + slkf2); \
      a[m_][3] = *(const long*)(p_ + slkf3); \
    } } while (0)
#define RD_B8(D, NH, DST) do { _Pragma("unroll") \
    for (int n_ = 0; n_ < 2; ++n_) { \
      const char* p_ = lds + (D) * 32768 + rowB0 + (NH) * 16384 + n_ * 2048; \
      DST[n_][0] = *(const long*)(p_ + slkf0); \
      DST[n_][1] = *(const long*)(p_ + slkf1); \
      DST[n_][2] = *(const long*)(p_ + slkf2); \
      DST[n_][3] = *(const long*)(p_ + slkf3); \
    } } while (0)
#define MFMA32F8(MH, NH, BSRC) do { \
    __builtin_amdgcn_s_setprio(1); \
    _Pragma("unroll") for (int m_ = 0; m_ < 4; ++m_) \
    _Pragma("unroll") for (int n_ = 0; n_ < 2; ++n_) \
    _Pragma("unroll") for (int k_ = 0; k_ < 4; ++k_) \
      acc[(MH) * 4 + m_][(NH) * 2 + n_] = __builtin_amdgcn_mfma_f32_16x16x32_fp8_fp8( \
          a[m_][k_], BSRC[n_][k_], acc[(MH) * 4 + m_][(NH) * 2 + n_], 0, 0, 0); \
    __builtin_amdgcn_s_setprio(0); } while (0)

  STG_A8(0, 0, 0); STG_A8(0, 0, 2);
  STG_B8(0, 0, 0, 0); STG_B8(0, 0, 0, 1);
  STG_B8(0, 0, 1, 0); STG_B8(0, 0, 1, 1);
  STG_A8(0, 0, 1); STG_A8(0, 0, 3);
  WAIT_VMN(0);
  SBAR(); SCHED_FENCE();

  for (int kt = 0; kt < nt - 1; ++kt) {
    const int d = kt & 1, dn = d ^ 1;
    RD_A8(d, 0); RD_B8(d, 0, b0);
    STG_A8(dn, kt + 1, 0); STG_A8(dn, kt + 1, 2);
    SBAR(); WAIT_LGKM0(); SCHED_FENCE();
    MFMA32F8(0, 0, b0);
    SBAR(); SCHED_FENCE();
    RD_B8(d, 1, b1);
    STG_B8(dn, kt + 1, 0, 0); STG_B8(dn, kt + 1, 0, 1);
    WAIT_VMN(4);
    SBAR(); WAIT_LGKM0(); SCHED_FENCE();
    MFMA32F8(0, 1, b1);
    SBAR(); SCHED_FENCE();
    RD_A8(d, 1);
    STG_B8(dn, kt + 1, 1, 0); STG_B8(dn, kt + 1, 1, 1);
    SBAR(); WAIT_LGKM0(); SCHED_FENCE();
    MFMA32F8(1, 0, b0);
    SBAR(); SCHED_FENCE();
    STG_A8(dn, kt + 1, 1); STG_A8(dn, kt + 1, 3);
    MFMA32F8(1, 1, b1);
    WAIT_VMN(2);
    SBAR(); SCHED_FENCE();
  }

  {
    const int d = (nt - 1) & 1;
    RD_A8(d, 0); RD_B8(d, 0, b0);
    SBAR(); WAIT_LGKM0(); SCHED_FENCE();
    MFMA32F8(0, 0, b0);
    SBAR(); SCHED_FENCE();
    RD_B8(d, 1, b1);
    WAIT_VMN(0);
    SBAR(); WAIT_LGKM0(); SCHED_FENCE();
    MFMA32F8(0, 1, b1);
    SBAR(); SCHED_FENCE();
    RD_A8(d, 1);
    WAIT_LGKM0(); SCHED_FENCE();
    MFMA32F8(1, 0, b0);
    MFMA32F8(1, 1, b1);
  }
#undef STG_A8
#undef STG_B8
#undef RD_A8
#undef RD_B8
#undef MFMA32F8

  const int lr4 = lhi << 2;
#pragma unroll
  for (int m = 0; m < 8; ++m) {
#pragma unroll
    for (int n = 0; n < 4; ++n) {
      const int c_i = col0 + wc * 64 + n * 16 + ln15;
      const float bv = bias[c_i];
#pragma unroll
      for (int j = 0; j < 4; ++j) {
        const int r_i = row0 + wr * 128 + m * 16 + lr4 + j;
        const size_t idx = (size_t)r_i * N + c_i;
        float val = acc[m][n][j] * 0.25f + bv;   // undo x4 weight scale
        if constexpr (EPI == 2) {
          ((float*)outp)[idx] = val + resid[idx];
        } else {
          const float u  = 0.7978845608028654f * (val + 0.044715f * val * val * val);
          const float th = 1.f - 2.f / (__expf(2.f * u) + 1.f);
          ((uint8_t*)outp)[idx] = to_fp8(0.5f * val * (1.f + th));
        }
      }
    }
  }
}

// ---------------------------------------------------------------------------
// kv partials, roles swapped so output is kvT[e][d] = sum_t v[t,e]*kf[t,d].
// ---------------------------------------------------------------------------
__global__ __launch_bounds__(256) void kv_part_kernel(
    const bf16* __restrict__ qkv, float* __restrict__ kv_part,
    float* __restrict__ ksum_part)
{
  const int bh = blockIdx.x >> 3, ch = blockIdx.x & 7;
  const int b = bh >> 4, h = bh & 15;
  const int tid = threadIdx.x;
  const int d = tid & 63, eg = tid >> 6;
  const size_t grow0 = (size_t)b * 4096 + (size_t)ch * 512;
  const size_t vbase = 2048 + (size_t)h * 64;
  __shared__ bf16 svv[8][64], skf[8][64];
  float accum[16];
#pragma unroll
  for (int i = 0; i < 16; ++i) accum[i] = 0.f;
  float ks = 0.f;
  const int tt = tid >> 5, cc = (tid & 31) << 1;
  for (int t0 = 0; t0 < 512; t0 += 8) {
    __syncthreads();
    const size_t base = (grow0 + t0 + tt) * 3072 + vbase + cc;
    *(uint32_t*)&svv[tt][cc] = *(const uint32_t*)(qkv + base);          // V
    *(uint32_t*)&skf[tt][cc] = *(const uint32_t*)(qkv + base - 1024);   // KF
    __syncthreads();
#pragma unroll
    for (int q = 0; q < 8; ++q) {
      const float kd = (float)skf[q][d];
      const uint32_t* u0 = (const uint32_t*)&svv[q][eg * 16];
#pragma unroll
      for (int i = 0; i < 8; ++i) {
        const uint32_t u = u0[i];
        const float lo = __uint_as_float(u << 16);
        const float hi = __uint_as_float(u & 0xffff0000u);
        accum[2 * i]     += lo * kd;
        accum[2 * i + 1] += hi * kd;
      }
    }
    if (tid < 64) {
#pragma unroll
      for (int q = 0; q < 8; ++q) ks += (float)skf[q][tid];
    }
  }
  float* op = kv_part + (size_t)blockIdx.x * 4096 + (size_t)(eg * 16) * 64 + d;
#pragma unroll
  for (int ee = 0; ee < 16; ++ee) op[ee * 64] = accum[ee];
  if (tid < 64) ksum_part[(size_t)blockIdx.x * 64 + tid] = ks;
}

// ---------------------------------------------------------------------------
// reduce partials -> bf16 B-tile KB[80][64] per head:
// rows 0-63 = kvT[e][d], row 64 = ksum[d], rows 65-79 = 0.
// ---------------------------------------------------------------------------
__global__ __launch_bounds__(256) void kv_reduce(
    const float* __restrict__ kvp, const float* __restrict__ ksp,
    bf16* __restrict__ kb)
{
  const int bh = blockIdx.x;
  const int tid = threadIdx.x;
  bf16* KB = kb + (size_t)bh * 5120;
  for (int i = tid; i < 4096; i += 256) {
    float s = 0.f;
#pragma unroll
    for (int ch = 0; ch < 8; ++ch) s += kvp[((size_t)bh * 8 + ch) * 4096 + i];
    KB[i] = (bf16)s;
  }
  if (tid < 64) {
    float s = 0.f;
#pragma unroll
    for (int ch = 0; ch < 8; ++ch) s += ksp[((size_t)bh * 8 + ch) * 64 + tid];
    KB[4096 + tid] = (bf16)s;
  }
  for (int i = 4160 + tid; i < 5120; i += 256) KB[i] = (bf16)0.f;
}

// ---------------------------------------------------------------------------
// attn out via MFMA (16x16x32): out[r][e] = (qf.kvT)[r][e] / (qf.ksum + 1e-6)
// ---------------------------------------------------------------------------
__global__ __launch_bounds__(256) void attn_mfma(
    const bf16* __restrict__ qkv, const bf16* __restrict__ kb,
    bf16* __restrict__ attn)
{
  const int bh = blockIdx.x >> 4, rb = blockIdx.x & 15;
  const int b = bh >> 4, h = bh & 15;
  const int tid = threadIdx.x, wid = tid >> 6, lane = tid & 63;
  const int ln15 = lane & 15, lhi = lane >> 4;
  const size_t row0 = (size_t)b * 4096 + rb * 256 + wid * 64;
  const bf16* KB = kb + (size_t)bh * 5120;

  bf16x8 bfr[5][2];
#pragma unroll
  for (int nb = 0; nb < 5; ++nb)
#pragma unroll
    for (int ks = 0; ks < 2; ++ks)
      bfr[nb][ks] = *(const bf16x8*)(KB + (nb * 16 + ln15) * 64 + ks * 32 + lhi * 8);

  for (int mt = 0; mt < 4; ++mt) {
    const bf16* ap = qkv + (row0 + mt * 16 + ln15) * 3072 + h * 64 + lhi * 8;
    const bf16x8 a0 = *(const bf16x8*)ap;
    const bf16x8 a1 = *(const bf16x8*)(ap + 32);
    f32x4 acc[5];
#pragma unroll
    for (int nb = 0; nb < 5; ++nb) {
      f32x4 z = {0.f, 0.f, 0.f, 0.f};
      z = __builtin_amdgcn_mfma_f32_16x16x32_bf16(a0, bfr[nb][0], z, 0, 0, 0);
      acc[nb] = __builtin_amdgcn_mfma_f32_16x16x32_bf16(a1, bfr[nb][1], z, 0, 0, 0);
    }
#pragma unroll
    for (int j = 0; j < 4; ++j) {
      const float ns = __shfl(acc[4][j], (lane & 48));
      const float inv = 1.f / (ns + 1e-6f);
      const size_t r = row0 + mt * 16 + (lhi << 2) + j;
#pragma unroll
      for (int nb = 0; nb < 4; ++nb)
        attn[r * 1024 + h * 64 + nb * 16 + ln15] = (bf16)(acc[nb][j] * inv);
    }
  }
}

// ---------------------------------------------------------------------------
// launch
// ---------------------------------------------------------------------------
extern "C" void kernel_launch(void* const* d_in, const int* in_sizes, int n_in,
                              void* d_out, int out_size, void* d_ws, size_t ws_size,
                              hipStream_t stream)
{
  const float* x    = (const float*)d_in[0];
  const float* ln1w = (const float*)d_in[1];
  const float* ln1b = (const float*)d_in[2];
  const float* qw   = (const float*)d_in[3];
  const float* qb   = (const float*)d_in[4];
  const float* kw   = (const float*)d_in[5];
  const float* kb_  = (const float*)d_in[6];
  const float* vw   = (const float*)d_in[7];
  const float* vb   = (const float*)d_in[8];
  const float* ow   = (const float*)d_in[9];
  const float* ob   = (const float*)d_in[10];
  const float* ln2w = (const float*)d_in[11];
  const float* ln2b = (const float*)d_in[12];
  const float* fcw  = (const float*)d_in[13];
  const float* fcb  = (const float*)d_in[14];
  const float* pjw  = (const float*)d_in[15];
  const float* pjb  = (const float*)d_in[16];
  float* out = (float*)d_out;
  char* ws = (char*)d_ws;

  constexpr size_t O_LNX  = 0;
  constexpr size_t O_QKV  = 33554432;
  constexpr size_t O_HMLP = 0;           // fp8 hmlp, 64MB
  constexpr size_t O_KVP  = 134217728;
  constexpr size_t O_KSP  = 142606336;
  constexpr size_t O_KB   = 142737408;
  constexpr size_t O_ATTN = 143802368;
  constexpr size_t O_LN2  = 177356800;   // fp8 ln2h, 16MB
  constexpr size_t O_WQ   = 210911232;
  constexpr size_t O_WO   = 217202688;
  constexpr size_t O_WFC  = 219299840;   // fp8 fc weight, 4MB
  constexpr size_t O_WPJ  = 227688448;   // fp8 proj weight, 4MB

  bf16* lnx    = (bf16*)(ws + O_LNX);
  bf16* qkv    = (bf16*)(ws + O_QKV);
  uint8_t* hmlp8 = (uint8_t*)(ws + O_HMLP);
  float* kvp   = (float*)(ws + O_KVP);
  float* qkvb  = (float*)(ws + O_KVP);   // 12KB, dead before kv_part runs
  float* ksp   = (float*)(ws + O_KSP);
  bf16* kbt    = (bf16*)(ws + O_KB);
  bf16* attn   = (bf16*)(ws + O_ATTN);
  uint8_t* ln2h8 = (uint8_t*)(ws + O_LN2);
  bf16* wqkvT  = (bf16*)(ws + O_WQ);
  bf16* woT    = (bf16*)(ws + O_WO);
  uint8_t* wfc8 = (uint8_t*)(ws + O_WFC);
  uint8_t* wpj8 = (uint8_t*)(ws + O_WPJ);

  const dim3 tb(32, 8);
  transpose4<<<dim3(32, 32, 4), tb, 0, stream>>>(qw, kw, vw, ow, wqkvT, woT);
  transpose_cast_f8<<<dim3(128, 32), tb, 0, stream>>>(fcw, wfc8, 1024, 4096, 4.f);
  transpose_cast_f8<<<dim3(32, 128), tb, 0, stream>>>(pjw, wpj8, 4096, 1024, 4.f);
  pack3<<<12, 256, 0, stream>>>(qb, kb_, vb, qkvb);

  ln_row<0><<<16384, 256, 0, stream>>>(x, ln1w, ln1b, lnx);

  // fused q|k|v projection: [16384,1024] x [1024,3072] (bf16)
  gemm256<4><<<768, 512, 0, stream>>>(lnx, wqkvT, qkvb, nullptr, qkv, 16384, 3072, 1024, 12);

  kv_part_kernel<<<512, 256, 0, stream>>>(qkv, kvp, ksp);
  kv_reduce<<<64, 256, 0, stream>>>(kvp, ksp, kbt);
  attn_mfma<<<1024, 256, 0, stream>>>(qkv, kbt, attn);

  // y1 = x + attn @ o_w + o_b   (f32 into d_out, bf16 GEMM)
  gemm256<2><<<256, 512, 0, stream>>>(attn, woT, ob, x, out, 16384, 1024, 1024, 4);

  ln_row<1><<<16384, 256, 0, stream>>>(out, ln2w, ln2b, ln2h8);

  // fc: fp8 x fp8 -> gelu -> fp8 hmlp
  gemm256f8<3><<<1024, 512, 0, stream>>>(ln2h8, wfc8, fcb, nullptr, hmlp8, 16384, 4096, 1024, 16);

  // proj: fp8 x fp8 + resid -> f32 (in-place on d_out: read-before-write)
  gemm256f8<2><<<256, 512, 0, stream>>>(hmlp8, wpj8, pjb, out, out, 16384, 1024, 4096, 4);
}

// Round 11
// 725.932 us; speedup vs baseline: 1.1208x; 1.0548x over previous
//
#include <hip/hip_runtime.h>
#include <hip/hip_bf16.h>
#include <cstdint>
#include <cstddef>

typedef __bf16 bf16;
typedef __bf16 bf16x8 __attribute__((ext_vector_type(8)));
typedef __bf16 bf16x4 __attribute__((ext_vector_type(4)));
typedef float  f32x4  __attribute__((ext_vector_type(4)));
typedef long   lx2    __attribute__((ext_vector_type(2)));

typedef __attribute__((address_space(1))) void gvoid_t;
typedef __attribute__((address_space(3))) void lvoid_t;

// async global->LDS, 16B per lane; LDS dest must be wave-uniform base (HW adds lane*16)
#define GLD_LDS16(g, l) __builtin_amdgcn_global_load_lds( \
    (gvoid_t*)(uintptr_t)(g), (lvoid_t*)(uint32_t)(uintptr_t)(l), 16, 0, 0)

#define SBAR() __builtin_amdgcn_s_barrier()
#define SCHED_FENCE() __builtin_amdgcn_sched_barrier(0)
#define WAIT_VMN(n) asm volatile("s_waitcnt vmcnt(" #n ")" ::: "memory")
#define WAIT_LGKM0() asm volatile("s_waitcnt lgkmcnt(0)" ::: "memory")

// ---------------------------------------------------------------------------
// float -> OCP e4m3fn, RNE, saturating.
// ---------------------------------------------------------------------------
__device__ inline uint8_t to_fp8(float x)
{
  uint32_t u = __float_as_uint(x);
  const uint8_t s = (u >> 24) & 0x80u;
  const int e = (int)((u >> 23) & 0xff) - 127;
  const uint32_t m = u & 0x7fffffu;
  if (((u >> 23) & 0xff) == 0xff) return s | 0x7e;            // inf/nan -> sat
  if (e > 8 || (e == 8 && m > 0x600000u)) return s | 0x7e;    // |x|>448 -> 448
  if (e >= -6) {                                              // normal fp8
    uint32_t mant = m >> 20;
    const uint32_t rest = m & 0xfffffu;
    const uint32_t rnd = (rest > 0x80000u) || (rest == 0x80000u && (mant & 1));
    mant += rnd;
    uint32_t ee = (uint32_t)(e + 7);
    if (mant == 8) { mant = 0; ee += 1; }
    if (ee > 15 || (ee == 15 && mant > 6)) return s | 0x7e;
    return s | (ee << 3) | mant;
  }
  if (e < -10) return s;                                      // -> +-0
  const int sh = 20 + (-6 - e);                               // 21..24
  const uint32_t sig = 0x800000u | m;
  uint32_t mant = sig >> sh;
  const uint32_t rem = sig & ((1u << sh) - 1u);
  const uint32_t half = 1u << (sh - 1);
  const uint32_t rnd = (rem > half) || (rem == half && (mant & 1));
  mant += rnd;
  if (mant >= 8) return s | (1u << 3);
  return s | mant;
}

// k-permutation within each 128-elem block: k=64a+32b+8c+d -> p=64a+16c+8b+d.
// Unit u=p>>4 = 4t+lhi then holds lane lhi's bytes for k-steps {2t,2t+1}
// (first 8B = ks even, second 8B = ks odd) -> frag reads become single b128.
__device__ inline int pi128(int k)
{
  return ((k >> 6) << 6) | (((k & 31) >> 3) << 4) | (((k >> 5) & 1) << 3) | (k & 7);
}

// ---------------------------------------------------------------------------
// 4x fused weight transpose + f32->bf16 cast (1024x1024 each)
// ---------------------------------------------------------------------------
__global__ __launch_bounds__(256) void transpose4(
    const float* __restrict__ qw, const float* __restrict__ kw,
    const float* __restrict__ vw, const float* __restrict__ ow,
    bf16* __restrict__ wqkvT, bf16* __restrict__ woT)
{
  __shared__ float tile[32][33];
  const int z = blockIdx.z;
  const float* in = z == 0 ? qw : (z == 1 ? kw : (z == 2 ? vw : ow));
  bf16* out = z == 3 ? woT : (wqkvT + (size_t)z * 1024 * 1024);
  const int bx = blockIdx.x, by = blockIdx.y;
  const int tx = threadIdx.x, ty = threadIdx.y;
#pragma unroll
  for (int i = 0; i < 32; i += 8)
    tile[ty + i][tx] = in[(size_t)(by * 32 + ty + i) * 1024 + bx * 32 + tx];
  __syncthreads();
#pragma unroll
  for (int i = 0; i < 32; i += 8)
    out[(size_t)(bx * 32 + ty + i) * 1024 + by * 32 + tx] = (bf16)tile[tx][ty + i];
}

// transpose + cast to fp8 with scale; k-coordinate stored pi128-permuted
__global__ __launch_bounds__(256) void transpose_cast_f8(
    const float* __restrict__ in, uint8_t* __restrict__ out, int R, int C,
    float scale)
{
  __shared__ float tile[32][33];
  const int bx = blockIdx.x, by = blockIdx.y;
  const int tx = threadIdx.x, ty = threadIdx.y;
#pragma unroll
  for (int i = 0; i < 32; i += 8)
    tile[ty + i][tx] = in[(size_t)(by * 32 + ty + i) * C + bx * 32 + tx];
  __syncthreads();
  const int kk = by * 32 + tx;
  const int kp = (kk & ~127) | pi128(kk & 127);
#pragma unroll
  for (int i = 0; i < 32; i += 8)
    out[(size_t)(bx * 32 + ty + i) * R + kp] = to_fp8(tile[tx][ty + i] * scale);
}

// pack q/k/v biases into one 3072-float vector
__global__ __launch_bounds__(256) void pack3(
    const float* __restrict__ a, const float* __restrict__ b,
    const float* __restrict__ c, float* __restrict__ o)
{
  const int i = blockIdx.x * 256 + threadIdx.x;
  o[i] = i < 1024 ? a[i] : (i < 2048 ? b[i - 1024] : c[i - 2048]);
}

// ---------------------------------------------------------------------------
// LayerNorm over H=1024, f32 in -> bf16 out (OUT8=0) or pi-permuted fp8 (OUT8=1).
// ---------------------------------------------------------------------------
template <int OUT8>
__global__ __launch_bounds__(256) void ln_row(
    const float* __restrict__ x, const float* __restrict__ w,
    const float* __restrict__ b, void* __restrict__ outp)
{
  const int row = blockIdx.x;
  const int tid = threadIdx.x;
  const float4 v = ((const float4*)(x + (size_t)row * 1024))[tid];
  float s  = v.x + v.y + v.z + v.w;
  float ss = v.x * v.x + v.y * v.y + v.z * v.z + v.w * v.w;
#pragma unroll
  for (int off = 32; off > 0; off >>= 1) {
    s  += __shfl_down(s, off);
    ss += __shfl_down(ss, off);
  }
  __shared__ float red[8];
  const int wid = tid >> 6, lane = tid & 63;
  if (lane == 0) { red[wid] = s; red[4 + wid] = ss; }
  __syncthreads();
  s  = red[0] + red[1] + red[2] + red[3];
  ss = red[4] + red[5] + red[6] + red[7];
  const float mu   = s * (1.f / 1024.f);
  const float var  = ss * (1.f / 1024.f) - mu * mu;
  const float rstd = rsqrtf(var + 1e-5f);
  const float4 wv = ((const float4*)w)[tid];
  const float4 bv = ((const float4*)b)[tid];
  float o0 = (v.x - mu) * rstd * wv.x + bv.x;
  float o1 = (v.y - mu) * rstd * wv.y + bv.y;
  float o2 = (v.z - mu) * rstd * wv.z + bv.z;
  float o3 = (v.w - mu) * rstd * wv.w + bv.w;
  if constexpr (OUT8) {
    uint8_t* out = (uint8_t*)outp;
    const int k0 = tid * 4;
    const int kp = (k0 & ~127) | pi128(k0 & 127);   // 4-aligned -> contiguous
    uchar4 q = {to_fp8(o0), to_fp8(o1), to_fp8(o2), to_fp8(o3)};
    *(uchar4*)(out + (size_t)row * 1024 + kp) = q;
  } else {
    bf16x4 ov; ov[0] = (bf16)o0; ov[1] = (bf16)o1; ov[2] = (bf16)o2; ov[3] = (bf16)o3;
    *(bf16x4*)((bf16*)outp + (size_t)row * 1024 + tid * 4) = ov;
  }
}

// ---------------------------------------------------------------------------
// 256x256 bf16 GEMM, BK=64, 8 waves (2Mx4N), r6/r7 4-phase schedule (best).
// EPI: 0 bias->bf16 | 1 bias->elu+1->bf16 | 2 bias+resid->f32 |
//      4 qkv merged (col<2048 elu+1, else plain)
// ---------------------------------------------------------------------------
template <int EPI>
__global__ __launch_bounds__(512, 2) void gemm256(
    const bf16* __restrict__ A, const bf16* __restrict__ BT,
    const float* __restrict__ bias, const float* __restrict__ resid,
    void* __restrict__ outp, int M, int N, int K, int nx)
{
  __shared__ __align__(16) char lds[131072];
  const int tid  = threadIdx.x;
  const int wid  = tid >> 6, lane = tid & 63;
  const int wr   = wid >> 2, wc = wid & 3;
  const int ln15 = lane & 15, lhi = lane >> 4;

  const int nwg = (int)gridDim.x;
  const int cpx = nwg >> 3;
  const int bid = (int)blockIdx.x;
  const int lg  = (bid & 7) * cpx + (bid >> 3);
  const int bx  = lg % nx, by = lg / nx;
  const int row0 = by << 8, col0 = bx << 8;

  const int srowA = tid >> 3;
  const int sslA  = (tid & 7) ^ (srowA & 7);
  const bf16* aS  = A + (size_t)(row0 + srowA) * K + sslA * 8;
  const size_t rjK = (size_t)K << 6;
  const int u8    = tid >> 3, s8 = tid & 7;
  const int gRowB = ((u8 >> 5) << 6) + (u8 & 31);
  const int sslB  = s8 ^ (u8 & 7);
  const bf16* bS  = BT + (size_t)(col0 + gRowB) * K + sslB * 8;

  char* ldsAw = lds + wid * 1024;
  char* ldsBw = lds + 65536 + wid * 1024;

  const int slk0 = (lhi ^ (ln15 & 7)) << 4;
  const int slk1 = ((4 + lhi) ^ (ln15 & 7)) << 4;
  const int rowA0 = ((wr << 7) + ln15) * 128;
  const int rowB0 = 65536 + (wc * 32 + ln15) * 128;

  f32x4 acc[8][4] = {};
  bf16x8 a[4][2], b0[2][2], b1[2][2];
  const int nt = K >> 6;

#define STG_A(D, KT, I) GLD_LDS16(aS + (size_t)(I) * rjK + (size_t)(KT) * 64, \
                                  ldsAw + (D) * 32768 + (I) * 8192)
#define STG_B(D, KT, NH, J) GLD_LDS16(bS + (size_t)((J) * 128 + (NH) * 32) * K + (size_t)(KT) * 64, \
                                      ldsBw + (D) * 32768 + (NH) * 16384 + (J) * 8192)
#define RD_A(D, MH) do { _Pragma("unroll") \
    for (int m_ = 0; m_ < 4; ++m_) { \
      a[m_][0] = *(const bf16x8*)(lds + (D) * 32768 + rowA0 + (MH) * 8192 + m_ * 2048 + slk0); \
      a[m_][1] = *(const bf16x8*)(lds + (D) * 32768 + rowA0 + (MH) * 8192 + m_ * 2048 + slk1); \
    } } while (0)
#define RD_B(D, NH, DST) do { _Pragma("unroll") \
    for (int n_ = 0; n_ < 2; ++n_) { \
      DST[n_][0] = *(const bf16x8*)(lds + (D) * 32768 + rowB0 + (NH) * 16384 + n_ * 2048 + slk0); \
      DST[n_][1] = *(const bf16x8*)(lds + (D) * 32768 + rowB0 + (NH) * 16384 + n_ * 2048 + slk1); \
    } } while (0)
#define MFMA8(MH, NH, BSRC) do { \
    __builtin_amdgcn_s_setprio(1); \
    _Pragma("unroll") for (int m_ = 0; m_ < 4; ++m_) \
    _Pragma("unroll") for (int n_ = 0; n_ < 2; ++n_) { \
      acc[(MH) * 4 + m_][(NH) * 2 + n_] = __builtin_amdgcn_mfma_f32_16x16x32_bf16( \
          a[m_][0], BSRC[n_][0], acc[(MH) * 4 + m_][(NH) * 2 + n_], 0, 0, 0); \
      acc[(MH) * 4 + m_][(NH) * 2 + n_] = __builtin_amdgcn_mfma_f32_16x16x32_bf16( \
          a[m_][1], BSRC[n_][1], acc[(MH) * 4 + m_][(NH) * 2 + n_], 0, 0, 0); \
    } \
    __builtin_amdgcn_s_setprio(0); } while (0)

  STG_A(0, 0, 0); STG_A(0, 0, 2);
  STG_B(0, 0, 0, 0); STG_B(0, 0, 0, 1);
  STG_B(0, 0, 1, 0); STG_B(0, 0, 1, 1);
  STG_A(0, 0, 1); STG_A(0, 0, 3);
  WAIT_VMN(0);
  SBAR(); SCHED_FENCE();

  for (int kt = 0; kt < nt - 1; ++kt) {
    const int d = kt & 1, dn = d ^ 1;
    RD_A(d, 0); RD_B(d, 0, b0);
    STG_A(dn, kt + 1, 0); STG_A(dn, kt + 1, 2);
    SBAR(); WAIT_LGKM0(); SCHED_FENCE();
    MFMA8(0, 0, b0);
    SBAR(); SCHED_FENCE();
    RD_B(d, 1, b1);
    STG_B(dn, kt + 1, 0, 0); STG_B(dn, kt + 1, 0, 1);
    WAIT_VMN(4);
    SBAR(); WAIT_LGKM0(); SCHED_FENCE();
    MFMA8(0, 1, b1);
    SBAR(); SCHED_FENCE();
    RD_A(d, 1);
    STG_B(dn, kt + 1, 1, 0); STG_B(dn, kt + 1, 1, 1);
    SBAR(); WAIT_LGKM0(); SCHED_FENCE();
    MFMA8(1, 0, b0);
    SBAR(); SCHED_FENCE();
    STG_A(dn, kt + 1, 1); STG_A(dn, kt + 1, 3);
    MFMA8(1, 1, b1);
    WAIT_VMN(2);
    SBAR(); SCHED_FENCE();
  }

  {
    const int d = (nt - 1) & 1;
    RD_A(d, 0); RD_B(d, 0, b0);
    SBAR(); WAIT_LGKM0(); SCHED_FENCE();
    MFMA8(0, 0, b0);
    SBAR(); SCHED_FENCE();
    RD_B(d, 1, b1);
    WAIT_VMN(0);
    SBAR(); WAIT_LGKM0(); SCHED_FENCE();
    MFMA8(0, 1, b1);
    SBAR(); SCHED_FENCE();
    RD_A(d, 1);
    WAIT_LGKM0(); SCHED_FENCE();
    MFMA8(1, 0, b0);
    MFMA8(1, 1, b1);
  }
#undef STG_A
#undef STG_B
#undef RD_A
#undef RD_B
#undef MFMA8

  const int lr4 = lhi << 2;
#pragma unroll
  for (int m = 0; m < 8; ++m) {
#pragma unroll
    for (int n = 0; n < 4; ++n) {
      const int c_i = col0 + wc * 64 + n * 16 + ln15;
      const float bv = bias[c_i];
#pragma unroll
      for (int j = 0; j < 4; ++j) {
        const int r_i = row0 + wr * 128 + m * 16 + lr4 + j;
        const size_t idx = (size_t)r_i * N + c_i;
        float val = acc[m][n][j] + bv;
        if constexpr (EPI == 0) {
          ((bf16*)outp)[idx] = (bf16)val;
        } else if constexpr (EPI == 1) {
          ((bf16*)outp)[idx] = (bf16)(val > 0.f ? val + 1.f : __expf(val));
        } else if constexpr (EPI == 2) {
          ((float*)outp)[idx] = val + resid[idx];
        } else {
          if (c_i < 2048)
            ((bf16*)outp)[idx] = (bf16)(val > 0.f ? val + 1.f : __expf(val));
          else
            ((bf16*)outp)[idx] = (bf16)val;
        }
      }
    }
  }
}

// ---------------------------------------------------------------------------
// 256x256 fp8-e4m3 GEMM v3: BK=128 (128B rows), operands stored pi128-permuted
// so every frag read is ONE ds_read_b128 at slot (t*4+lhi)^(row&7) — byte-
// identical bank geometry to the proven-0-conflict bf16 kernel. Each b128
// (lx2) holds k-steps {2t,2t+1}: .x feeds ks even, .y ks odd.
// Same staging / 4-phase ledger as bf16. Weights pre-scaled x4 -> epi x0.25.
// EPI: 2 = +bias+resid->f32 | 3 = +bias->gelu->fp8 (pi-permuted out)
// ---------------------------------------------------------------------------
template <int EPI>
__global__ __launch_bounds__(512, 2) void gemm256f8(
    const uint8_t* __restrict__ A, const uint8_t* __restrict__ BT,
    const float* __restrict__ bias, const float* __restrict__ resid,
    void* __restrict__ outp, int M, int N, int K, int nx)
{
  __shared__ __align__(16) char lds[131072];
  const int tid  = threadIdx.x;
  const int wid  = tid >> 6, lane = tid & 63;
  const int wr   = wid >> 2, wc = wid & 3;
  const int ln15 = lane & 15, lhi = lane >> 4;

  const int nwg = (int)gridDim.x;
  const int cpx = nwg >> 3;
  const int bid = (int)blockIdx.x;
  const int lg  = (bid & 7) * cpx + (bid >> 3);
  const int bx  = lg % nx, by = lg / nx;
  const int row0 = by << 8, col0 = bx << 8;

  const int srowA = tid >> 3;
  const int sslA  = (tid & 7) ^ (srowA & 7);
  const uint8_t* aS = A + (size_t)(row0 + srowA) * K + sslA * 16;
  const size_t rjK = (size_t)K << 6;          // 64 rows (bytes)
  const int u8    = tid >> 3, s8 = tid & 7;
  const int gRowB = ((u8 >> 5) << 6) + (u8 & 31);
  const int sslB  = s8 ^ (u8 & 7);
  const uint8_t* bS = BT + (size_t)(col0 + gRowB) * K + sslB * 16;

  char* ldsAw = lds + wid * 1024;
  char* ldsBw = lds + 65536 + wid * 1024;

  // b128 read offsets: slot (t*4+lhi)^(row&7), identical form to bf16 slk0/1
  const int e7 = ln15 & 7;
  const int slkT0 = (lhi ^ e7) << 4;
  const int slkT1 = ((4 + lhi) ^ e7) << 4;
  const int rowA0 = wr * 16384 + ln15 * 128;            // + MH*8192 + m*2048
  const int rowB0 = 65536 + wc * 4096 + ln15 * 128;     // + NH*16384 + n*2048

  f32x4 acc[8][4] = {};
  lx2 a[4][2], b0[2][2], b1[2][2];
  const int nt = K >> 7;

#define STG_A8(D, KT, I) GLD_LDS16(aS + (size_t)(I) * rjK + (size_t)(KT) * 128, \
                                   ldsAw + (D) * 32768 + (I) * 8192)
#define STG_B8(D, KT, NH, J) GLD_LDS16(bS + (size_t)((J) * 128 + (NH) * 32) * K + (size_t)(KT) * 128, \
                                       ldsBw + (D) * 32768 + (NH) * 16384 + (J) * 8192)
#define RD_A8(D, MH) do { _Pragma("unroll") \
    for (int m_ = 0; m_ < 4; ++m_) { \
      const char* p_ = lds + (D) * 32768 + rowA0 + (MH) * 8192 + m_ * 2048; \
      a[m_][0] = *(const lx2*)(p_ + slkT0); \
      a[m_][1] = *(const lx2*)(p_ + slkT1); \
    } } while (0)
#define RD_B8(D, NH, DST) do { _Pragma("unroll") \
    for (int n_ = 0; n_ < 2; ++n_) { \
      const char* p_ = lds + (D) * 32768 + rowB0 + (NH) * 16384 + n_ * 2048; \
      DST[n_][0] = *(const lx2*)(p_ + slkT0); \
      DST[n_][1] = *(const lx2*)(p_ + slkT1); \
    } } while (0)
#define MFMA32F8(MH, NH, BSRC) do { \
    __builtin_amdgcn_s_setprio(1); \
    _Pragma("unroll") for (int m_ = 0; m_ < 4; ++m_) \
    _Pragma("unroll") for (int n_ = 0; n_ < 2; ++n_) { \
      acc[(MH) * 4 + m_][(NH) * 2 + n_] = __builtin_amdgcn_mfma_f32_16x16x32_fp8_fp8( \
          a[m_][0].x, BSRC[n_][0].x, acc[(MH) * 4 + m_][(NH) * 2 + n_], 0, 0, 0); \
      acc[(MH) * 4 + m_][(NH) * 2 + n_] = __builtin_amdgcn_mfma_f32_16x16x32_fp8_fp8( \
          a[m_][0].y, BSRC[n_][0].y, acc[(MH) * 4 + m_][(NH) * 2 + n_], 0, 0, 0); \
      acc[(MH) * 4 + m_][(NH) * 2 + n_] = __builtin_amdgcn_mfma_f32_16x16x32_fp8_fp8( \
          a[m_][1].x, BSRC[n_][1].x, acc[(MH) * 4 + m_][(NH) * 2 + n_], 0, 0, 0); \
      acc[(MH) * 4 + m_][(NH) * 2 + n_] = __builtin_amdgcn_mfma_f32_16x16x32_fp8_fp8( \
          a[m_][1].y, BSRC[n_][1].y, acc[(MH) * 4 + m_][(NH) * 2 + n_], 0, 0, 0); \
    } \
    __builtin_amdgcn_s_setprio(0); } while (0)

  STG_A8(0, 0, 0); STG_A8(0, 0, 2);
  STG_B8(0, 0, 0, 0); STG_B8(0, 0, 0, 1);
  STG_B8(0, 0, 1, 0); STG_B8(0, 0, 1, 1);
  STG_A8(0, 0, 1); STG_A8(0, 0, 3);
  WAIT_VMN(0);
  SBAR(); SCHED_FENCE();

  for (int kt = 0; kt < nt - 1; ++kt) {
    const int d = kt & 1, dn = d ^ 1;
    RD_A8(d, 0); RD_B8(d, 0, b0);
    STG_A8(dn, kt + 1, 0); STG_A8(dn, kt + 1, 2);
    SBAR(); WAIT_LGKM0(); SCHED_FENCE();
    MFMA32F8(0, 0, b0);
    SBAR(); SCHED_FENCE();
    RD_B8(d, 1, b1);
    STG_B8(dn, kt + 1, 0, 0); STG_B8(dn, kt + 1, 0, 1);
    WAIT_VMN(4);
    SBAR(); WAIT_LGKM0(); SCHED_FENCE();
    MFMA32F8(0, 1, b1);
    SBAR(); SCHED_FENCE();
    RD_A8(d, 1);
    STG_B8(dn, kt + 1, 1, 0); STG_B8(dn, kt + 1, 1, 1);
    SBAR(); WAIT_LGKM0(); SCHED_FENCE();
    MFMA32F8(1, 0, b0);
    SBAR(); SCHED_FENCE();
    STG_A8(dn, kt + 1, 1); STG_A8(dn, kt + 1, 3);
    MFMA32F8(1, 1, b1);
    WAIT_VMN(2);
    SBAR(); SCHED_FENCE();
  }

  {
    const int d = (nt - 1) & 1;
    RD_A8(d, 0); RD_B8(d, 0, b0);
    SBAR(); WAIT_LGKM0(); SCHED_FENCE();
    MFMA32F8(0, 0, b0);
    SBAR(); SCHED_FENCE();
    RD_B8(d, 1, b1);
    WAIT_VMN(0);
    SBAR(); WAIT_LGKM0(); SCHED_FENCE();
    MFMA32F8(0, 1, b1);
    SBAR(); SCHED_FENCE();
    RD_A8(d, 1);
    WAIT_LGKM0(); SCHED_FENCE();
    MFMA32F8(1, 0, b0);
    MFMA32F8(1, 1, b1);
  }
#undef STG_A8
#undef STG_B8
#undef RD_A8
#undef RD_B8
#undef MFMA32F8

  const int lr4 = lhi << 2;
#pragma unroll
  for (int m = 0; m < 8; ++m) {
#pragma unroll
    for (int n = 0; n < 4; ++n) {
      const int c_i = col0 + wc * 64 + n * 16 + ln15;
      const float bv = bias[c_i];
#pragma unroll
      for (int j = 0; j < 4; ++j) {
        const int r_i = row0 + wr * 128 + m * 16 + lr4 + j;
        float val = acc[m][n][j] * 0.25f + bv;   // undo x4 weight scale
        if constexpr (EPI == 2) {
          const size_t idx = (size_t)r_i * N + c_i;
          ((float*)outp)[idx] = val + resid[idx];
        } else {
          // gelu -> fp8, written pi128-permuted (consumed as proj's A)
          const float u  = 0.7978845608028654f * (val + 0.044715f * val * val * val);
          const float th = 1.f - 2.f / (__expf(2.f * u) + 1.f);
          const int cp = (c_i & ~127) | pi128(c_i & 127);
          ((uint8_t*)outp)[(size_t)r_i * N + cp] = to_fp8(0.5f * val * (1.f + th));
        }
      }
    }
  }
}

// ---------------------------------------------------------------------------
// kv partials, roles swapped so output is kvT[e][d] = sum_t v[t,e]*kf[t,d].
// ---------------------------------------------------------------------------
__global__ __launch_bounds__(256) void kv_part_kernel(
    const bf16* __restrict__ qkv, float* __restrict__ kv_part,
    float* __restrict__ ksum_part)
{
  const int bh = blockIdx.x >> 3, ch = blockIdx.x & 7;
  const int b = bh >> 4, h = bh & 15;
  const int tid = threadIdx.x;
  const int d = tid & 63, eg = tid >> 6;
  const size_t grow0 = (size_t)b * 4096 + (size_t)ch * 512;
  const size_t vbase = 2048 + (size_t)h * 64;
  __shared__ bf16 svv[8][64], skf[8][64];
  float accum[16];
#pragma unroll
  for (int i = 0; i < 16; ++i) accum[i] = 0.f;
  float ks = 0.f;
  const int tt = tid >> 5, cc = (tid & 31) << 1;
  for (int t0 = 0; t0 < 512; t0 += 8) {
    __syncthreads();
    const size_t base = (grow0 + t0 + tt) * 3072 + vbase + cc;
    *(uint32_t*)&svv[tt][cc] = *(const uint32_t*)(qkv + base);          // V
    *(uint32_t*)&skf[tt][cc] = *(const uint32_t*)(qkv + base - 1024);   // KF
    __syncthreads();
#pragma unroll
    for (int q = 0; q < 8; ++q) {
      const float kd = (float)skf[q][d];
      const uint32_t* u0 = (const uint32_t*)&svv[q][eg * 16];
#pragma unroll
      for (int i = 0; i < 8; ++i) {
        const uint32_t u = u0[i];
        const float lo = __uint_as_float(u << 16);
        const float hi = __uint_as_float(u & 0xffff0000u);
        accum[2 * i]     += lo * kd;
        accum[2 * i + 1] += hi * kd;
      }
    }
    if (tid < 64) {
#pragma unroll
      for (int q = 0; q < 8; ++q) ks += (float)skf[q][tid];
    }
  }
  float* op = kv_part + (size_t)blockIdx.x * 4096 + (size_t)(eg * 16) * 64 + d;
#pragma unroll
  for (int ee = 0; ee < 16; ++ee) op[ee * 64] = accum[ee];
  if (tid < 64) ksum_part[(size_t)blockIdx.x * 64 + tid] = ks;
}

// ---------------------------------------------------------------------------
// reduce partials -> bf16 B-tile KB[80][64] per head:
// rows 0-63 = kvT[e][d], row 64 = ksum[d], rows 65-79 = 0.
// ---------------------------------------------------------------------------
__global__ __launch_bounds__(256) void kv_reduce(
    const float* __restrict__ kvp, const float* __restrict__ ksp,
    bf16* __restrict__ kb)
{
  const int bh = blockIdx.x;
  const int tid = threadIdx.x;
  bf16* KB = kb + (size_t)bh * 5120;
  for (int i = tid; i < 4096; i += 256) {
    float s = 0.f;
#pragma unroll
    for (int ch = 0; ch < 8; ++ch) s += kvp[((size_t)bh * 8 + ch) * 4096 + i];
    KB[i] = (bf16)s;
  }
  if (tid < 64) {
    float s = 0.f;
#pragma unroll
    for (int ch = 0; ch < 8; ++ch) s += ksp[((size_t)bh * 8 + ch) * 64 + tid];
    KB[4096 + tid] = (bf16)s;
  }
  for (int i = 4160 + tid; i < 5120; i += 256) KB[i] = (bf16)0.f;
}

// ---------------------------------------------------------------------------
// attn out via MFMA (16x16x32): out[r][e] = (qf.kvT)[r][e] / (qf.ksum + 1e-6)
// ---------------------------------------------------------------------------
__global__ __launch_bounds__(256) void attn_mfma(
    const bf16* __restrict__ qkv, const bf16* __restrict__ kb,
    bf16* __restrict__ attn)
{
  const int bh = blockIdx.x >> 4, rb = blockIdx.x & 15;
  const int b = bh >> 4, h = bh & 15;
  const int tid = threadIdx.x, wid = tid >> 6, lane = tid & 63;
  const int ln15 = lane & 15, lhi = lane >> 4;
  const size_t row0 = (size_t)b * 4096 + rb * 256 + wid * 64;
  const bf16* KB = kb + (size_t)bh * 5120;

  bf16x8 bfr[5][2];
#pragma unroll
  for (int nb = 0; nb < 5; ++nb)
#pragma unroll
    for (int ks = 0; ks < 2; ++ks)
      bfr[nb][ks] = *(const bf16x8*)(KB + (nb * 16 + ln15) * 64 + ks * 32 + lhi * 8);

  for (int mt = 0; mt < 4; ++mt) {
    const bf16* ap = qkv + (row0 + mt * 16 + ln15) * 3072 + h * 64 + lhi * 8;
    const bf16x8 a0 = *(const bf16x8*)ap;
    const bf16x8 a1 = *(const bf16x8*)(ap + 32);
    f32x4 acc[5];
#pragma unroll
    for (int nb = 0; nb < 5; ++nb) {
      f32x4 z = {0.f, 0.f, 0.f, 0.f};
      z = __builtin_amdgcn_mfma_f32_16x16x32_bf16(a0, bfr[nb][0], z, 0, 0, 0);
      acc[nb] = __builtin_amdgcn_mfma_f32_16x16x32_bf16(a1, bfr[nb][1], z, 0, 0, 0);
    }
#pragma unroll
    for (int j = 0; j < 4; ++j) {
      const float ns = __shfl(acc[4][j], (lane & 48));
      const float inv = 1.f / (ns + 1e-6f);
      const size_t r = row0 + mt * 16 + (lhi << 2) + j;
#pragma unroll
      for (int nb = 0; nb < 4; ++nb)
        attn[r * 1024 + h * 64 + nb * 16 + ln15] = (bf16)(acc[nb][j] * inv);
    }
  }
}

// ---------------------------------------------------------------------------
// launch
// ---------------------------------------------------------------------------
extern "C" void kernel_launch(void* const* d_in, const int* in_sizes, int n_in,
                              void* d_out, int out_size, void* d_ws, size_t ws_size,
                              hipStream_t stream)
{
  const float* x    = (const float*)d_in[0];
  const float* ln1w = (const float*)d_in[1];
  const float* ln1b = (const float*)d_in[2];
  const float* qw   = (const float*)d_in[3];
  const float* qb   = (const float*)d_in[4];
  const float* kw   = (const float*)d_in[5];
  const float* kb_  = (const float*)d_in[6];
  const float* vw   = (const float*)d_in[7];
  const float* vb   = (const float*)d_in[8];
  const float* ow   = (const float*)d_in[9];
  const float* ob   = (const float*)d_in[10];
  const float* ln2w = (const float*)d_in[11];
  const float* ln2b = (const float*)d_in[12];
  const float* fcw  = (const float*)d_in[13];
  const float* fcb  = (const float*)d_in[14];
  const float* pjw  = (const float*)d_in[15];
  const float* pjb  = (const float*)d_in[16];
  float* out = (float*)d_out;
  char* ws = (char*)d_ws;

  constexpr size_t O_LNX  = 0;
  constexpr size_t O_QKV  = 33554432;
  constexpr size_t O_HMLP = 0;           // fp8 hmlp, 64MB
  constexpr size_t O_KVP  = 134217728;
  constexpr size_t O_KSP  = 142606336;
  constexpr size_t O_KB   = 142737408;
  constexpr size_t O_ATTN = 143802368;
  constexpr size_t O_LN2  = 177356800;   // fp8 ln2h, 16MB
  constexpr size_t O_WQ   = 210911232;
  constexpr size_t O_WO   = 217202688;
  constexpr size_t O_WFC  = 219299840;   // fp8 fc weight, 4MB
  constexpr size_t O_WPJ  = 227688448;   // fp8 proj weight, 4MB

  bf16* lnx    = (bf16*)(ws + O_LNX);
  bf16* qkv    = (bf16*)(ws + O_QKV);
  uint8_t* hmlp8 = (uint8_t*)(ws + O_HMLP);
  float* kvp   = (float*)(ws + O_KVP);
  float* qkvb  = (float*)(ws + O_KVP);   // 12KB, dead before kv_part runs
  float* ksp   = (float*)(ws + O_KSP);
  bf16* kbt    = (bf16*)(ws + O_KB);
  bf16* attn   = (bf16*)(ws + O_ATTN);
  uint8_t* ln2h8 = (uint8_t*)(ws + O_LN2);
  bf16* wqkvT  = (bf16*)(ws + O_WQ);
  bf16* woT    = (bf16*)(ws + O_WO);
  uint8_t* wfc8 = (uint8_t*)(ws + O_WFC);
  uint8_t* wpj8 = (uint8_t*)(ws + O_WPJ);

  const dim3 tb(32, 8);
  transpose4<<<dim3(32, 32, 4), tb, 0, stream>>>(qw, kw, vw, ow, wqkvT, woT);
  transpose_cast_f8<<<dim3(128, 32), tb, 0, stream>>>(fcw, wfc8, 1024, 4096, 4.f);
  transpose_cast_f8<<<dim3(32, 128), tb, 0, stream>>>(pjw, wpj8, 4096, 1024, 4.f);
  pack3<<<12, 256, 0, stream>>>(qb, kb_, vb, qkvb);

  ln_row<0><<<16384, 256, 0, stream>>>(x, ln1w, ln1b, lnx);

  // fused q|k|v projection: [16384,1024] x [1024,3072] (bf16)
  gemm256<4><<<768, 512, 0, stream>>>(lnx, wqkvT, qkvb, nullptr, qkv, 16384, 3072, 1024, 12);

  kv_part_kernel<<<512, 256, 0, stream>>>(qkv, kvp, ksp);
  kv_reduce<<<64, 256, 0, stream>>>(kvp, ksp, kbt);
  attn_mfma<<<1024, 256, 0, stream>>>(qkv, kbt, attn);

  // y1 = x + attn @ o_w + o_b   (f32 into d_out, bf16 GEMM)
  gemm256<2><<<256, 512, 0, stream>>>(attn, woT, ob, x, out, 16384, 1024, 1024, 4);

  ln_row<1><<<16384, 256, 0, stream>>>(out, ln2w, ln2b, ln2h8);

  // fc: fp8 x fp8 -> gelu -> fp8 hmlp (pi-permuted)
  gemm256f8<3><<<1024, 512, 0, stream>>>(ln2h8, wfc8, fcb, nullptr, hmlp8, 16384, 4096, 1024, 16);

  // proj: fp8 x fp8 + resid -> f32 (in-place on d_out: read-before-write)
  gemm256f8<2><<<256, 512, 0, stream>>>(hmlp8, wpj8, pjb, out, out, 16384, 1024, 4096, 4);
}

// Round 12
// 602.539 us; speedup vs baseline: 1.3503x; 1.2048x over previous
//
#include <hip/hip_runtime.h>
#include <hip/hip_bf16.h>
#include <cstdint>
#include <cstddef>

typedef __bf16 bf16;
typedef __bf16 bf16x8 __attribute__((ext_vector_type(8)));
typedef __bf16 bf16x4 __attribute__((ext_vector_type(4)));
typedef float  f32x4  __attribute__((ext_vector_type(4)));

typedef __attribute__((address_space(1))) void gvoid_t;
typedef __attribute__((address_space(3))) void lvoid_t;

// async global->LDS, 16B per lane; LDS dest must be wave-uniform base (HW adds lane*16)
#define GLD_LDS16(g, l) __builtin_amdgcn_global_load_lds( \
    (gvoid_t*)(uintptr_t)(g), (lvoid_t*)(uint32_t)(uintptr_t)(l), 16, 0, 0)

#define SBAR() __builtin_amdgcn_s_barrier()
#define SCHED_FENCE() __builtin_amdgcn_sched_barrier(0)
#define WAIT_VMN(n) asm volatile("s_waitcnt vmcnt(" #n ")" ::: "memory")
#define WAIT_LGKM0() asm volatile("s_waitcnt lgkmcnt(0)" ::: "memory")

// ---------------------------------------------------------------------------
// 4x fused weight transpose + f32->bf16 cast (1024x1024 each): q,k,v -> wqkvT
// (contiguous), o -> woT.
// ---------------------------------------------------------------------------
__global__ __launch_bounds__(256) void transpose4(
    const float* __restrict__ qw, const float* __restrict__ kw,
    const float* __restrict__ vw, const float* __restrict__ ow,
    bf16* __restrict__ wqkvT, bf16* __restrict__ woT)
{
  __shared__ float tile[32][33];
  const int z = blockIdx.z;
  const float* in = z == 0 ? qw : (z == 1 ? kw : (z == 2 ? vw : ow));
  bf16* out = z == 3 ? woT : (wqkvT + (size_t)z * 1024 * 1024);
  const int bx = blockIdx.x, by = blockIdx.y;
  const int tx = threadIdx.x, ty = threadIdx.y;
#pragma unroll
  for (int i = 0; i < 32; i += 8)
    tile[ty + i][tx] = in[(size_t)(by * 32 + ty + i) * 1024 + bx * 32 + tx];
  __syncthreads();
#pragma unroll
  for (int i = 0; i < 32; i += 8)
    out[(size_t)(bx * 32 + ty + i) * 1024 + by * 32 + tx] = (bf16)tile[tx][ty + i];
}

// general transpose for fc/proj weights
__global__ __launch_bounds__(256) void transpose_cast(
    const float* __restrict__ in, bf16* __restrict__ out, int R, int C)
{
  __shared__ float tile[32][33];
  const int bx = blockIdx.x, by = blockIdx.y;
  const int tx = threadIdx.x, ty = threadIdx.y;
#pragma unroll
  for (int i = 0; i < 32; i += 8)
    tile[ty + i][tx] = in[(size_t)(by * 32 + ty + i) * C + bx * 32 + tx];
  __syncthreads();
#pragma unroll
  for (int i = 0; i < 32; i += 8)
    out[(size_t)(bx * 32 + ty + i) * R + by * 32 + tx] = (bf16)tile[tx][ty + i];
}

// pack q/k/v biases into one 3072-float vector
__global__ __launch_bounds__(256) void pack3(
    const float* __restrict__ a, const float* __restrict__ b,
    const float* __restrict__ c, float* __restrict__ o)
{
  const int i = blockIdx.x * 256 + threadIdx.x;
  o[i] = i < 1024 ? a[i] : (i < 2048 ? b[i - 1024] : c[i - 2048]);
}

// ---------------------------------------------------------------------------
// LayerNorm over H=1024, f32 in -> bf16 out. One block (256 thr) per row.
// ---------------------------------------------------------------------------
__global__ __launch_bounds__(256) void ln_row(
    const float* __restrict__ x, const float* __restrict__ w,
    const float* __restrict__ b, bf16* __restrict__ out)
{
  const int row = blockIdx.x;
  const int tid = threadIdx.x;
  const float4 v = ((const float4*)(x + (size_t)row * 1024))[tid];
  float s  = v.x + v.y + v.z + v.w;
  float ss = v.x * v.x + v.y * v.y + v.z * v.z + v.w * v.w;
#pragma unroll
  for (int off = 32; off > 0; off >>= 1) {
    s  += __shfl_down(s, off);
    ss += __shfl_down(ss, off);
  }
  __shared__ float red[8];
  const int wid = tid >> 6, lane = tid & 63;
  if (lane == 0) { red[wid] = s; red[4 + wid] = ss; }
  __syncthreads();
  s  = red[0] + red[1] + red[2] + red[3];
  ss = red[4] + red[5] + red[6] + red[7];
  const float mu   = s * (1.f / 1024.f);
  const float var  = ss * (1.f / 1024.f) - mu * mu;
  const float rstd = rsqrtf(var + 1e-5f);
  const float4 wv = ((const float4*)w)[tid];
  const float4 bv = ((const float4*)b)[tid];
  bf16x4 ov;
  ov[0] = (bf16)((v.x - mu) * rstd * wv.x + bv.x);
  ov[1] = (bf16)((v.y - mu) * rstd * wv.y + bv.y);
  ov[2] = (bf16)((v.z - mu) * rstd * wv.z + bv.z);
  ov[3] = (bf16)((v.w - mu) * rstd * wv.w + bv.w);
  *(bf16x4*)(out + (size_t)row * 1024 + tid * 4) = ov;
}

// ---------------------------------------------------------------------------
// 256x256 GEMM, BK=64, 8 waves (2Mx4N), 4-phase/K-tile schedule (r6 best).
// Phases: P1{read Ah0+Bh0(12), stage Ah0'}, P2{read Bh1(4), stage Bh0', vm(4)},
//         P3{read Ah1(8), stage Bh1'}, P4{stage Ah1', MFMA, vm(2)}.
// 8-slot XOR swizzle (slot ^= row&7) on BOTH gld source and ds_read -> 0 bc.
// EPI: 0 bias->bf16 | 1 bias->elu+1->bf16 | 2 bias+resid->f32 |
//      3 bias->gelu->bf16 | 4 qkv merged (col<2048 elu+1, else plain)
// ---------------------------------------------------------------------------
template <int EPI>
__global__ __launch_bounds__(512, 2) void gemm256(
    const bf16* __restrict__ A, const bf16* __restrict__ BT,
    const float* __restrict__ bias, const float* __restrict__ resid,
    void* __restrict__ outp, int M, int N, int K, int nx)
{
  __shared__ __align__(16) char lds[131072];
  const int tid  = threadIdx.x;
  const int wid  = tid >> 6, lane = tid & 63;
  const int wr   = wid >> 2, wc = wid & 3;
  const int ln15 = lane & 15, lhi = lane >> 4;

  const int nwg = (int)gridDim.x;
  const int cpx = nwg >> 3;
  const int bid = (int)blockIdx.x;
  const int lg  = (bid & 7) * cpx + (bid >> 3);
  const int bx  = lg % nx, by = lg / nx;
  const int row0 = by << 8, col0 = bx << 8;

  const int srowA = tid >> 3;
  const int sslA  = (tid & 7) ^ (srowA & 7);
  const bf16* aS  = A + (size_t)(row0 + srowA) * K + sslA * 8;
  const size_t rjK = (size_t)K << 6;
  const int u8    = tid >> 3, s8 = tid & 7;
  const int gRowB = ((u8 >> 5) << 6) + (u8 & 31);
  const int sslB  = s8 ^ (u8 & 7);
  const bf16* bS  = BT + (size_t)(col0 + gRowB) * K + sslB * 8;

  char* ldsAw = lds + wid * 1024;
  char* ldsBw = lds + 65536 + wid * 1024;

  const int slk0 = (lhi ^ (ln15 & 7)) << 4;
  const int slk1 = ((4 + lhi) ^ (ln15 & 7)) << 4;
  const int rowA0 = ((wr << 7) + ln15) * 128;
  const int rowB0 = 65536 + (wc * 32 + ln15) * 128;

  f32x4 acc[8][4] = {};
  bf16x8 a[4][2], b0[2][2], b1[2][2];
  const int nt = K >> 6;

#define STG_A(D, KT, I) GLD_LDS16(aS + (size_t)(I) * rjK + (size_t)(KT) * 64, \
                                  ldsAw + (D) * 32768 + (I) * 8192)
#define STG_B(D, KT, NH, J) GLD_LDS16(bS + (size_t)((J) * 128 + (NH) * 32) * K + (size_t)(KT) * 64, \
                                      ldsBw + (D) * 32768 + (NH) * 16384 + (J) * 8192)
#define RD_A(D, MH) do { _Pragma("unroll") \
    for (int m_ = 0; m_ < 4; ++m_) { \
      a[m_][0] = *(const bf16x8*)(lds + (D) * 32768 + rowA0 + (MH) * 8192 + m_ * 2048 + slk0); \
      a[m_][1] = *(const bf16x8*)(lds + (D) * 32768 + rowA0 + (MH) * 8192 + m_ * 2048 + slk1); \
    } } while (0)
#define RD_B(D, NH, DST) do { _Pragma("unroll") \
    for (int n_ = 0; n_ < 2; ++n_) { \
      DST[n_][0] = *(const bf16x8*)(lds + (D) * 32768 + rowB0 + (NH) * 16384 + n_ * 2048 + slk0); \
      DST[n_][1] = *(const bf16x8*)(lds + (D) * 32768 + rowB0 + (NH) * 16384 + n_ * 2048 + slk1); \
    } } while (0)
#define MFMA8(MH, NH, BSRC) do { \
    __builtin_amdgcn_s_setprio(1); \
    _Pragma("unroll") for (int m_ = 0; m_ < 4; ++m_) \
    _Pragma("unroll") for (int n_ = 0; n_ < 2; ++n_) { \
      acc[(MH) * 4 + m_][(NH) * 2 + n_] = __builtin_amdgcn_mfma_f32_16x16x32_bf16( \
          a[m_][0], BSRC[n_][0], acc[(MH) * 4 + m_][(NH) * 2 + n_], 0, 0, 0); \
      acc[(MH) * 4 + m_][(NH) * 2 + n_] = __builtin_amdgcn_mfma_f32_16x16x32_bf16( \
          a[m_][1], BSRC[n_][1], acc[(MH) * 4 + m_][(NH) * 2 + n_], 0, 0, 0); \
    } \
    __builtin_amdgcn_s_setprio(0); } while (0)

  STG_A(0, 0, 0); STG_A(0, 0, 2);
  STG_B(0, 0, 0, 0); STG_B(0, 0, 0, 1);
  STG_B(0, 0, 1, 0); STG_B(0, 0, 1, 1);
  STG_A(0, 0, 1); STG_A(0, 0, 3);
  WAIT_VMN(0);
  SBAR(); SCHED_FENCE();

  for (int kt = 0; kt < nt - 1; ++kt) {
    const int d = kt & 1, dn = d ^ 1;
    RD_A(d, 0); RD_B(d, 0, b0);
    STG_A(dn, kt + 1, 0); STG_A(dn, kt + 1, 2);
    SBAR(); WAIT_LGKM0(); SCHED_FENCE();
    MFMA8(0, 0, b0);
    SBAR(); SCHED_FENCE();
    RD_B(d, 1, b1);
    STG_B(dn, kt + 1, 0, 0); STG_B(dn, kt + 1, 0, 1);
    WAIT_VMN(4);
    SBAR(); WAIT_LGKM0(); SCHED_FENCE();
    MFMA8(0, 1, b1);
    SBAR(); SCHED_FENCE();
    RD_A(d, 1);
    STG_B(dn, kt + 1, 1, 0); STG_B(dn, kt + 1, 1, 1);
    SBAR(); WAIT_LGKM0(); SCHED_FENCE();
    MFMA8(1, 0, b0);
    SBAR(); SCHED_FENCE();
    STG_A(dn, kt + 1, 1); STG_A(dn, kt + 1, 3);
    MFMA8(1, 1, b1);
    WAIT_VMN(2);
    SBAR(); SCHED_FENCE();
  }

  {
    const int d = (nt - 1) & 1;
    RD_A(d, 0); RD_B(d, 0, b0);
    SBAR(); WAIT_LGKM0(); SCHED_FENCE();
    MFMA8(0, 0, b0);
    SBAR(); SCHED_FENCE();
    RD_B(d, 1, b1);
    WAIT_VMN(0);
    SBAR(); WAIT_LGKM0(); SCHED_FENCE();
    MFMA8(0, 1, b1);
    SBAR(); SCHED_FENCE();
    RD_A(d, 1);
    WAIT_LGKM0(); SCHED_FENCE();
    MFMA8(1, 0, b0);
    MFMA8(1, 1, b1);
  }
#undef STG_A
#undef STG_B
#undef RD_A
#undef RD_B
#undef MFMA8

  const int lr4 = lhi << 2;
#pragma unroll
  for (int m = 0; m < 8; ++m) {
#pragma unroll
    for (int n = 0; n < 4; ++n) {
      const int c_i = col0 + wc * 64 + n * 16 + ln15;
      const float bv = bias[c_i];
#pragma unroll
      for (int j = 0; j < 4; ++j) {
        const int r_i = row0 + wr * 128 + m * 16 + lr4 + j;
        const size_t idx = (size_t)r_i * N + c_i;
        float val = acc[m][n][j] + bv;
        if constexpr (EPI == 0) {
          ((bf16*)outp)[idx] = (bf16)val;
        } else if constexpr (EPI == 1) {
          ((bf16*)outp)[idx] = (bf16)(val > 0.f ? val + 1.f : __expf(val));
        } else if constexpr (EPI == 2) {
          ((float*)outp)[idx] = val + resid[idx];
        } else if constexpr (EPI == 3) {
          const float u  = 0.7978845608028654f * (val + 0.044715f * val * val * val);
          const float th = 1.f - 2.f / (__expf(2.f * u) + 1.f);
          ((bf16*)outp)[idx] = (bf16)(0.5f * val * (1.f + th));
        } else {
          if (c_i < 2048)
            ((bf16*)outp)[idx] = (bf16)(val > 0.f ? val + 1.f : __expf(val));
          else
            ((bf16*)outp)[idx] = (bf16)val;
        }
      }
    }
  }
}

// ---------------------------------------------------------------------------
// kv partials, roles swapped so output is kvT[e][d] = sum_t v[t,e]*kf[t,d].
// ---------------------------------------------------------------------------
__global__ __launch_bounds__(256) void kv_part_kernel(
    const bf16* __restrict__ qkv, float* __restrict__ kv_part,
    float* __restrict__ ksum_part)
{
  const int bh = blockIdx.x >> 3, ch = blockIdx.x & 7;
  const int b = bh >> 4, h = bh & 15;
  const int tid = threadIdx.x;
  const int d = tid & 63, eg = tid >> 6;
  const size_t grow0 = (size_t)b * 4096 + (size_t)ch * 512;
  const size_t vbase = 2048 + (size_t)h * 64;
  __shared__ bf16 svv[8][64], skf[8][64];
  float accum[16];
#pragma unroll
  for (int i = 0; i < 16; ++i) accum[i] = 0.f;
  float ks = 0.f;
  const int tt = tid >> 5, cc = (tid & 31) << 1;
  for (int t0 = 0; t0 < 512; t0 += 8) {
    __syncthreads();
    const size_t base = (grow0 + t0 + tt) * 3072 + vbase + cc;
    *(uint32_t*)&svv[tt][cc] = *(const uint32_t*)(qkv + base);          // V
    *(uint32_t*)&skf[tt][cc] = *(const uint32_t*)(qkv + base - 1024);   // KF
    __syncthreads();
#pragma unroll
    for (int q = 0; q < 8; ++q) {
      const float kd = (float)skf[q][d];
      const uint32_t* u0 = (const uint32_t*)&svv[q][eg * 16];
#pragma unroll
      for (int i = 0; i < 8; ++i) {
        const uint32_t u = u0[i];
        const float lo = __uint_as_float(u << 16);
        const float hi = __uint_as_float(u & 0xffff0000u);
        accum[2 * i]     += lo * kd;
        accum[2 * i + 1] += hi * kd;
      }
    }
    if (tid < 64) {
#pragma unroll
      for (int q = 0; q < 8; ++q) ks += (float)skf[q][tid];
    }
  }
  float* op = kv_part + (size_t)blockIdx.x * 4096 + (size_t)(eg * 16) * 64 + d;
#pragma unroll
  for (int ee = 0; ee < 16; ++ee) op[ee * 64] = accum[ee];
  if (tid < 64) ksum_part[(size_t)blockIdx.x * 64 + tid] = ks;
}

// ---------------------------------------------------------------------------
// reduce partials -> bf16 B-tile KB[80][64] per head:
// rows 0-63 = kvT[e][d], row 64 = ksum[d], rows 65-79 = 0.
// ---------------------------------------------------------------------------
__global__ __launch_bounds__(256) void kv_reduce(
    const float* __restrict__ kvp, const float* __restrict__ ksp,
    bf16* __restrict__ kb)
{
  const int bh = blockIdx.x;
  const int tid = threadIdx.x;
  bf16* KB = kb + (size_t)bh * 5120;
  for (int i = tid; i < 4096; i += 256) {
    float s = 0.f;
#pragma unroll
    for (int ch = 0; ch < 8; ++ch) s += kvp[((size_t)bh * 8 + ch) * 4096 + i];
    KB[i] = (bf16)s;
  }
  if (tid < 64) {
    float s = 0.f;
#pragma unroll
    for (int ch = 0; ch < 8; ++ch) s += ksp[((size_t)bh * 8 + ch) * 64 + tid];
    KB[4096 + tid] = (bf16)s;
  }
  for (int i = 4160 + tid; i < 5120; i += 256) KB[i] = (bf16)0.f;
}

// ---------------------------------------------------------------------------
// attn out via MFMA (16x16x32): out[r][e] = (qf.kvT)[r][e] / (qf.ksum + 1e-6)
// ---------------------------------------------------------------------------
__global__ __launch_bounds__(256) void attn_mfma(
    const bf16* __restrict__ qkv, const bf16* __restrict__ kb,
    bf16* __restrict__ attn)
{
  const int bh = blockIdx.x >> 4, rb = blockIdx.x & 15;
  const int b = bh >> 4, h = bh & 15;
  const int tid = threadIdx.x, wid = tid >> 6, lane = tid & 63;
  const int ln15 = lane & 15, lhi = lane >> 4;
  const size_t row0 = (size_t)b * 4096 + rb * 256 + wid * 64;
  const bf16* KB = kb + (size_t)bh * 5120;

  bf16x8 bfr[5][2];
#pragma unroll
  for (int nb = 0; nb < 5; ++nb)
#pragma unroll
    for (int ks = 0; ks < 2; ++ks)
      bfr[nb][ks] = *(const bf16x8*)(KB + (nb * 16 + ln15) * 64 + ks * 32 + lhi * 8);

  for (int mt = 0; mt < 4; ++mt) {
    const bf16* ap = qkv + (row0 + mt * 16 + ln15) * 3072 + h * 64 + lhi * 8;
    const bf16x8 a0 = *(const bf16x8*)ap;
    const bf16x8 a1 = *(const bf16x8*)(ap + 32);
    f32x4 acc[5];
#pragma unroll
    for (int nb = 0; nb < 5; ++nb) {
      f32x4 z = {0.f, 0.f, 0.f, 0.f};
      z = __builtin_amdgcn_mfma_f32_16x16x32_bf16(a0, bfr[nb][0], z, 0, 0, 0);
      acc[nb] = __builtin_amdgcn_mfma_f32_16x16x32_bf16(a1, bfr[nb][1], z, 0, 0, 0);
    }
#pragma unroll
    for (int j = 0; j < 4; ++j) {
      const float ns = __shfl(acc[4][j], (lane & 48));
      const float inv = 1.f / (ns + 1e-6f);
      const size_t r = row0 + mt * 16 + (lhi << 2) + j;
#pragma unroll
      for (int nb = 0; nb < 4; ++nb)
        attn[r * 1024 + h * 64 + nb * 16 + ln15] = (bf16)(acc[nb][j] * inv);
    }
  }
}

// ---------------------------------------------------------------------------
// launch
// ---------------------------------------------------------------------------
extern "C" void kernel_launch(void* const* d_in, const int* in_sizes, int n_in,
                              void* d_out, int out_size, void* d_ws, size_t ws_size,
                              hipStream_t stream)
{
  const float* x    = (const float*)d_in[0];
  const float* ln1w = (const float*)d_in[1];
  const float* ln1b = (const float*)d_in[2];
  const float* qw   = (const float*)d_in[3];
  const float* qb   = (const float*)d_in[4];
  const float* kw   = (const float*)d_in[5];
  const float* kb_  = (const float*)d_in[6];
  const float* vw   = (const float*)d_in[7];
  const float* vb   = (const float*)d_in[8];
  const float* ow   = (const float*)d_in[9];
  const float* ob   = (const float*)d_in[10];
  const float* ln2w = (const float*)d_in[11];
  const float* ln2b = (const float*)d_in[12];
  const float* fcw  = (const float*)d_in[13];
  const float* fcb  = (const float*)d_in[14];
  const float* pjw  = (const float*)d_in[15];
  const float* pjb  = (const float*)d_in[16];
  float* out = (float*)d_out;
  char* ws = (char*)d_ws;

  constexpr size_t O_LNX  = 0;
  constexpr size_t O_QKV  = 33554432;
  constexpr size_t O_HMLP = 0;
  constexpr size_t O_KVP  = 134217728;
  constexpr size_t O_KSP  = 142606336;
  constexpr size_t O_KB   = 142737408;
  constexpr size_t O_ATTN = 143802368;
  constexpr size_t O_LN2  = 177356800;
  constexpr size_t O_WQ   = 210911232;
  constexpr size_t O_WO   = 217202688;
  constexpr size_t O_WFC  = 219299840;
  constexpr size_t O_WPJ  = 227688448;

  bf16* lnx   = (bf16*)(ws + O_LNX);
  bf16* qkv   = (bf16*)(ws + O_QKV);
  bf16* hmlp  = (bf16*)(ws + O_HMLP);
  float* kvp  = (float*)(ws + O_KVP);
  float* qkvb = (float*)(ws + O_KVP);    // 12KB, dead before kv_part runs
  float* ksp  = (float*)(ws + O_KSP);
  bf16* kbt   = (bf16*)(ws + O_KB);
  bf16* attn  = (bf16*)(ws + O_ATTN);
  bf16* ln2h  = (bf16*)(ws + O_LN2);
  bf16* wqkvT = (bf16*)(ws + O_WQ);
  bf16* woT   = (bf16*)(ws + O_WO);
  bf16* wfcT  = (bf16*)(ws + O_WFC);
  bf16* wpjT  = (bf16*)(ws + O_WPJ);

  const dim3 tb(32, 8);
  transpose4<<<dim3(32, 32, 4), tb, 0, stream>>>(qw, kw, vw, ow, wqkvT, woT);
  transpose_cast<<<dim3(128, 32), tb, 0, stream>>>(fcw, wfcT, 1024, 4096);
  transpose_cast<<<dim3(32, 128), tb, 0, stream>>>(pjw, wpjT, 4096, 1024);
  pack3<<<12, 256, 0, stream>>>(qb, kb_, vb, qkvb);

  ln_row<<<16384, 256, 0, stream>>>(x, ln1w, ln1b, lnx);

  // fused q|k|v projection: [16384,1024] x [1024,3072]
  gemm256<4><<<768, 512, 0, stream>>>(lnx, wqkvT, qkvb, nullptr, qkv, 16384, 3072, 1024, 12);

  kv_part_kernel<<<512, 256, 0, stream>>>(qkv, kvp, ksp);
  kv_reduce<<<64, 256, 0, stream>>>(kvp, ksp, kbt);
  attn_mfma<<<1024, 256, 0, stream>>>(qkv, kbt, attn);

  // y1 = x + attn @ o_w + o_b   (f32 into d_out)
  gemm256<2><<<256, 512, 0, stream>>>(attn, woT, ob, x, out, 16384, 1024, 1024, 4);

  ln_row<<<16384, 256, 0, stream>>>(out, ln2w, ln2b, ln2h);

  gemm256<3><<<1024, 512, 0, stream>>>(ln2h, wfcT, fcb, nullptr, hmlp, 16384, 4096, 1024, 16);

  // out = y1 + h_mlp @ proj_w + proj_b  (in-place on d_out: read-before-write)
  gemm256<2><<<256, 512, 0, stream>>>(hmlp, wpjT, pjb, out, out, 16384, 1024, 4096, 4);
}